// Round 5
// baseline (184.752 us; speedup 1.0000x reference)
//
#include <hip/hip_runtime.h>
#include <cmath>

// ---------------- constants (match reference) ----------------
static constexpr int Tn = 1024, Dn = 512, Hn = 8, Cn = 64, DQn = 256,
                     NIn = 2, CIn = 64, TK = 32, LM = 16, NW = 128, Pn = 128;
#define NEGV (-1e30f)

typedef unsigned short u16;
typedef __bf16 bf16x8 __attribute__((ext_vector_type(8)));
typedef float f32x4 __attribute__((ext_vector_type(4)));

__device__ __forceinline__ u16 f2bf(float x) {
  unsigned u = __float_as_uint(x);
  return (u16)((u + 0x7fffu + ((u >> 16) & 1u)) >> 16);
}
__device__ __forceinline__ float bf2f(u16 b) {
  return __uint_as_float((unsigned)b << 16);
}

// ---------------- pack: fp32 -> split bf16 (hi+lo), k-grouped-by-8 ----------
// A-pack: src [1024][K] -> dst [K/8][1024][8] (plane), lo plane at dst+ps
// B-pack: src [K][N]    -> dst [K/8][N][8]
struct PackJobs {
  const float* src[7];
  u16* dst[7];
  int start[8];
  int N[7];
  int logN[7];
  int isA[7];
  int ps[7];  // plane size in u16 elements
};

__global__ __launch_bounds__(256) void pack_all(PackJobs pj) {
  int i = blockIdx.x * 256 + threadIdx.x;
  if (i >= pj.start[7]) return;
  int j = 0;
  while (i >= pj.start[j + 1]) ++j;
  int local = i - pj.start[j];
  const float* s = pj.src[j];
  u16* dh = pj.dst[j];
  u16* dl = dh + pj.ps[j];
  float x[8];
  if (pj.isA[j]) {
    int kg = local & 63;  // K=512 -> 64 kgroups
    int m = local >> 6;
    const float4* p = reinterpret_cast<const float4*>(s + (size_t)m * 512 + kg * 8);
    float4 a = p[0], b = p[1];
    x[0] = a.x; x[1] = a.y; x[2] = a.z; x[3] = a.w;
    x[4] = b.x; x[5] = b.y; x[6] = b.z; x[7] = b.w;
    union { u16 u[8]; int4 v; } oh, ol;
#pragma unroll
    for (int e = 0; e < 8; ++e) {
      u16 hb = f2bf(x[e]);
      oh.u[e] = hb;
      ol.u[e] = f2bf(x[e] - bf2f(hb));
    }
    size_t idx = ((size_t)kg * 1024 + m) * 8;
    *reinterpret_cast<int4*>(dh + idx) = oh.v;
    *reinterpret_cast<int4*>(dl + idx) = ol.v;
  } else {
    int N = pj.N[j];
    int n = local & (N - 1);
    int kg = local >> pj.logN[j];
#pragma unroll
    for (int e = 0; e < 8; ++e) x[e] = s[(size_t)(kg * 8 + e) * N + n];
    union { u16 u[8]; int4 v; } oh, ol;
#pragma unroll
    for (int e = 0; e < 8; ++e) {
      u16 hb = f2bf(x[e]);
      oh.u[e] = hb;
      ol.u[e] = f2bf(x[e] - bf2f(hb));
    }
    size_t idx = ((size_t)kg * N + n) * 8;
    *reinterpret_cast<int4*>(dh + idx) = oh.v;
    *reinterpret_cast<int4*>(dl + idx) = ol.v;
  }
}

// ---------------- split-bf16 MFMA GEMM ----------------
// 128x128 tile, 4 waves (64x64 quadrant each, 4x4 frags of 16x16x32), BK=32,
// double-buffered LDS, hi/lo planes, 3 MFMA per fragment pair:
//   AhBh + AlBh + AhBl  (error ~ eps_bf16^2)
struct TileDesc {
  const u16* Blo;  // hi-plane, N-half 0
  const u16* Bhi;  // hi-plane, N-half 1
  float* Clo;
  float* Chi;
  u16* Cp;
  int ldNlo, ldNhi, ldClo, ldChi, mode, n0, bps, cpps;
};
struct GemmArgs {
  TileDesc d[15];
};

#define GLD16(gp, lp)                                                     \
  __builtin_amdgcn_global_load_lds(                                      \
      (const __attribute__((address_space(1))) unsigned int*)(gp),       \
      (__attribute__((address_space(3))) unsigned int*)(lp), 16, 0, 0)

__global__ __launch_bounds__(256) void gemm_bf16(const u16* __restrict__ Ap,
                                                 int NK, int aps, GemmArgs ga) {
  const int ct = blockIdx.x, rt = blockIdx.y;
  const TileDesc d = ga.d[ct];
  const int m0 = rt * 128;
  __shared__ __align__(16) u16 lA[2][2][4][128][8];
  __shared__ __align__(16) u16 lB[2][2][4][128][8];
  const int tid = threadIdx.x;
  const int w = tid >> 6, lane = tid & 63;
  const int wm = w >> 1, wn = w & 1;

  f32x4 acc[4][4];
#pragma unroll
  for (int a = 0; a < 4; ++a)
#pragma unroll
    for (int b = 0; b < 4; ++b)
#pragma unroll
      for (int r = 0; r < 4; ++r) acc[a][b][r] = 0.f;

  auto stage = [&](int buf, int kg) {
    GLD16(Ap + ((size_t)kg * 1024 + m0 + lane) * 8, &lA[buf][0][w][0][0]);
    GLD16(Ap + ((size_t)kg * 1024 + m0 + 64 + lane) * 8, &lA[buf][0][w][64][0]);
    GLD16(Ap + aps + ((size_t)kg * 1024 + m0 + lane) * 8, &lA[buf][1][w][0][0]);
    GLD16(Ap + aps + ((size_t)kg * 1024 + m0 + 64 + lane) * 8, &lA[buf][1][w][64][0]);
    GLD16(d.Blo + ((size_t)kg * d.ldNlo + lane) * 8, &lB[buf][0][w][0][0]);
    GLD16(d.Bhi + ((size_t)kg * d.ldNhi + lane) * 8, &lB[buf][0][w][64][0]);
    GLD16(d.Blo + d.bps + ((size_t)kg * d.ldNlo + lane) * 8, &lB[buf][1][w][0][0]);
    GLD16(d.Bhi + d.bps + ((size_t)kg * d.ldNhi + lane) * 8, &lB[buf][1][w][64][0]);
  };

  stage(0, w);  // kgroup w of K-step 0
  const int kq = lane >> 4, fr = lane & 15;
  for (int ks = 0; ks < NK; ++ks) {
    __syncthreads();  // drains vmcnt -> buf[ks&1] staged; syncs prev compute
    if (ks + 1 < NK) stage((ks + 1) & 1, (ks + 1) * 4 + w);
    const int cb = ks & 1;
    bf16x8 aFh[4], aFl[4], bFh[4], bFl[4];
#pragma unroll
    for (int f = 0; f < 4; ++f) {
      aFh[f] = *reinterpret_cast<const bf16x8*>(&lA[cb][0][kq][wm * 64 + f * 16 + fr][0]);
      aFl[f] = *reinterpret_cast<const bf16x8*>(&lA[cb][1][kq][wm * 64 + f * 16 + fr][0]);
      bFh[f] = *reinterpret_cast<const bf16x8*>(&lB[cb][0][kq][wn * 64 + f * 16 + fr][0]);
      bFl[f] = *reinterpret_cast<const bf16x8*>(&lB[cb][1][kq][wn * 64 + f * 16 + fr][0]);
    }
#pragma unroll
    for (int fm = 0; fm < 4; ++fm)
#pragma unroll
      for (int fn = 0; fn < 4; ++fn) {
        acc[fm][fn] = __builtin_amdgcn_mfma_f32_16x16x32_bf16(aFh[fm], bFh[fn],
                                                              acc[fm][fn], 0, 0, 0);
        acc[fm][fn] = __builtin_amdgcn_mfma_f32_16x16x32_bf16(aFl[fm], bFh[fn],
                                                              acc[fm][fn], 0, 0, 0);
        acc[fm][fn] = __builtin_amdgcn_mfma_f32_16x16x32_bf16(aFh[fm], bFl[fn],
                                                              acc[fm][fn], 0, 0, 0);
      }
  }
  // epilogue: row = m0+wm*64+fm*16+(lane>>4)*4+r, col = wn*64+fn*16+(lane&15)
  float* Cb = (wn == 0) ? d.Clo : d.Chi;
  const int ldc = (wn == 0) ? d.ldClo : d.ldChi;
  if (d.mode != 1) {
#pragma unroll
    for (int fm = 0; fm < 4; ++fm)
#pragma unroll
      for (int fn = 0; fn < 4; ++fn)
#pragma unroll
        for (int r = 0; r < 4; ++r) {
          int row = m0 + wm * 64 + fm * 16 + (lane >> 4) * 4 + r;
          int cl = fn * 16 + fr;
          Cb[(size_t)row * ldc + cl] = acc[fm][fn][r];
        }
  }
  if (d.mode >= 1) {
#pragma unroll
    for (int fm = 0; fm < 4; ++fm)
#pragma unroll
      for (int fn = 0; fn < 4; ++fn)
#pragma unroll
        for (int r = 0; r < 4; ++r) {
          int row = m0 + wm * 64 + fm * 16 + (lane >> 4) * 4 + r;
          int gc = d.n0 + wn * 64 + fn * 16 + fr;
          float v = acc[fm][fn][r];
          u16 hb = f2bf(v);
          u16 lb = f2bf(v - bf2f(hb));
          size_t idx = ((size_t)(gc >> 3) * 1024 + row) * 8 + (gc & 7);
          d.Cp[idx] = hb;
          d.Cp[idx + d.cpps] = lb;
        }
  }
}

// ---------------- segmented fp32 GEMM (index path stays fp32) ----------------
struct SegParams {
  const float* B[6];
  float* C[6];
  int width[6];
  int tstart[6];
  int nseg;
};

__global__ __launch_bounds__(256) void sgemm_seg(const float* __restrict__ A,
                                                 int K, SegParams sp) {
  const int ct = blockIdx.x, rt = blockIdx.y;
  int s = 0;
  while (s + 1 < sp.nseg && ct >= sp.tstart[s + 1]) ++s;
  const float* __restrict__ Bm = sp.B[s];
  float* __restrict__ Cm = sp.C[s];
  const int ldb = sp.width[s];
  const int col0 = (ct - sp.tstart[s]) * 64;
  const int row0 = rt * 64;

  __shared__ float As[16][64];
  __shared__ float Bs[16][64];

  const int tid = threadIdx.x;
  const int tx = tid & 15, ty = tid >> 4;
  const int am = tid & 63, ak4 = (tid >> 6) << 2;
  const int bn4 = (tid & 15) << 2, bk = tid >> 4;

  float acc[4][4] = {};

  for (int k0 = 0; k0 < K; k0 += 16) {
    float4 av = *reinterpret_cast<const float4*>(&A[(row0 + am) * K + k0 + ak4]);
    As[ak4 + 0][am] = av.x;
    As[ak4 + 1][am] = av.y;
    As[ak4 + 2][am] = av.z;
    As[ak4 + 3][am] = av.w;
    *reinterpret_cast<float4*>(&Bs[bk][bn4]) =
        *reinterpret_cast<const float4*>(&Bm[(k0 + bk) * ldb + col0 + bn4]);
    __syncthreads();
#pragma unroll
    for (int k = 0; k < 16; ++k) {
      float4 a4 = *reinterpret_cast<const float4*>(&As[k][ty << 2]);
      float4 b4 = *reinterpret_cast<const float4*>(&Bs[k][tx << 2]);
      float a[4] = {a4.x, a4.y, a4.z, a4.w};
      float b[4] = {b4.x, b4.y, b4.z, b4.w};
#pragma unroll
      for (int i = 0; i < 4; ++i)
#pragma unroll
        for (int j = 0; j < 4; ++j) acc[i][j] += a[i] * b[j];
    }
    __syncthreads();
  }
#pragma unroll
  for (int i = 0; i < 4; ++i) {
    float4 v = make_float4(acc[i][0], acc[i][1], acc[i][2], acc[i][3]);
    *reinterpret_cast<float4*>(&Cm[(row0 + (ty << 2) + i) * ldb + col0 + (tx << 2)]) = v;
  }
}

// ---------------- phrase aggregation ----------------
__global__ __launch_bounds__(512) void phrase_kernel(
    const int* __restrict__ maskbuf, const int* __restrict__ tokbuf,
    const int* __restrict__ endbuf, const float* __restrict__ hckv,
    const float* __restrict__ hcz, const float* __restrict__ hikv,
    const float* __restrict__ hiz, const float* __restrict__ Bcsa,
    const float* __restrict__ Bidx, const float* __restrict__ knw,
    float* __restrict__ ccsa, float* __restrict__ kcsa,
    float* __restrict__ kidx) {
  const int p = blockIdx.x;
  const int tid = threadIdx.x;
  __shared__ int s_bytemode;
  __shared__ int s_tok[LM];
  __shared__ int s_m[LM];
  __shared__ int s_pos, s_anyv;

  if (tid == 0) s_bytemode = 0;
  __syncthreads();
  {
    unsigned w = ((const unsigned*)maskbuf)[tid];  // tid in [0,512)
    if (w > 1u) atomicOr(&s_bytemode, 1);
  }
  __syncthreads();
  const int bytemode = s_bytemode;
  if (tid < LM) {
    int mv;
    if (bytemode)
      mv = ((const unsigned char*)maskbuf)[p * LM + tid] != 0;
    else
      mv = maskbuf[p * LM + tid] != 0;
    s_m[tid] = mv;
    s_tok[tid] = tokbuf[p * LM + tid];
  }
  if (tid == 0) {
    int e = endbuf[p];
    s_pos = min(max(e, 0), Tn - 1);
  }
  __syncthreads();
  if (tid == 0) {
    int any = 0;
    for (int l = 0; l < LM; ++l) any |= s_m[l];
    s_anyv = any;
  }
  __syncthreads();
  const int anyv = s_anyv;
  const int pos = s_pos;
  const int c = tid & 63;
  const float fr = (float)pos * powf(10000.0f, -(float)(c & 31) / 32.0f);
  const float cv = cosf(fr), sv = sinf(fr);
  const float sgn = (c < 32) ? -1.f : 1.f;

  {
    float z[LM];
    float zmax = NEGV;
#pragma unroll
    for (int l = 0; l < LM; ++l) {
      float zv = hcz[s_tok[l] * Dn + tid] + Bcsa[l * (Hn * Cn) + tid];
      zv = s_m[l] ? zv : NEGV;
      z[l] = zv;
      zmax = fmaxf(zmax, zv);
    }
    float den = 0.f, num = 0.f;
#pragma unroll
    for (int l = 0; l < LM; ++l) {
      float e = expf(z[l] - zmax);
      den += e;
      num += e * hckv[s_tok[l] * Dn + tid];
    }
    float cc = anyv ? (num / den) : 0.f;
    ccsa[p * (Hn * Cn) + tid] = cc;

    float ss = cc * cc;
#pragma unroll
    for (int off = 32; off; off >>= 1) ss += __shfl_xor(ss, off, 64);
    float kn = cc * rsqrtf(ss / (float)Cn + 1e-6f) * knw[c];
    float pr = __shfl_xor(kn, 32, 64);
    kcsa[p * (Hn * Cn) + tid] = kn * cv + sgn * pr * sv;
  }

  if (tid < CIn) {
    float zk[LM];
    float zm = NEGV;
#pragma unroll
    for (int l = 0; l < LM; ++l) {
      float zv = hiz[s_tok[l] * CIn + tid] + Bidx[l * CIn + tid];
      zv = s_m[l] ? zv : NEGV;
      zk[l] = zv;
      zm = fmaxf(zm, zv);
    }
    float dk = 0.f, nk = 0.f;
#pragma unroll
    for (int l = 0; l < LM; ++l) {
      float e = expf(zk[l] - zm);
      dk += e;
      nk += e * hikv[s_tok[l] * CIn + tid];
    }
    float ki = anyv ? (nk / dk) : 0.f;
    float pr = __shfl_xor(ki, 32, 64);
    kidx[p * CIn + tid] = ki * cv + sgn * pr * sv;
  }
}

// ---------------- RMS+RoPE for q (in place) and k_sw ----------------
__global__ __launch_bounds__(512) void rmsrope_kernel(
    float* __restrict__ q, const float* __restrict__ kv,
    float* __restrict__ ksw, const float* __restrict__ qnw,
    const float* __restrict__ knw) {
  const int t = blockIdx.x;
  const int tid = threadIdx.x;
  const int c = tid & 63;
  const float fr = (float)t * powf(10000.0f, -(float)(c & 31) / 32.0f);
  const float cv = cosf(fr), sv = sinf(fr);
  const float sgn = (c < 32) ? -1.f : 1.f;
  {
    float x = q[t * Dn + tid];
    float ss = x * x;
#pragma unroll
    for (int off = 32; off; off >>= 1) ss += __shfl_xor(ss, off, 64);
    float xr = x * rsqrtf(ss / (float)Cn + 1e-6f) * qnw[c];
    float pr = __shfl_xor(xr, 32, 64);
    q[t * Dn + tid] = xr * cv + sgn * pr * sv;
  }
  {
    float y = kv[t * Dn + tid];
    float ss = y * y;
#pragma unroll
    for (int off = 32; off; off >>= 1) ss += __shfl_xor(ss, off, 64);
    float yr = y * rsqrtf(ss / (float)Cn + 1e-6f) * knw[c];
    float pr = __shfl_xor(yr, 32, 64);
    ksw[t * Dn + tid] = yr * cv + sgn * pr * sv;
  }
}

// ---------------- phrase scores + top-32 (all fp32) ----------------
__global__ __launch_bounds__(128) void score_topk_kernel(
    const float* __restrict__ hbuf, const float* __restrict__ Ww,
    const float* __restrict__ qi, const float* __restrict__ kidx,
    const int* __restrict__ endbuf, int* __restrict__ sel,
    int* __restrict__ selok) {
  const int t = blockIdx.x;
  const int tid = threadIdx.x;
  __shared__ float sqi[NIn * CIn];
  __shared__ float sI[Pn];
  __shared__ float sp0[128], sp1[128];

  sqi[tid] = qi[t * (NIn * CIn) + tid];
  float p0 = 0.f, p1 = 0.f;
#pragma unroll
  for (int e4 = 0; e4 < 4; ++e4) {
    int e = tid * 4 + e4;
    float hv = hbuf[t * Dn + e];
    p0 += hv * Ww[e * NIn + 0];
    p1 += hv * Ww[e * NIn + 1];
  }
  sp0[tid] = p0;
  sp1[tid] = p1;
  __syncthreads();
  for (int srd = 64; srd; srd >>= 1) {
    if (tid < srd) {
      sp0[tid] += sp0[tid + srd];
      sp1[tid] += sp1[tid + srd];
    }
    __syncthreads();
  }
  const float ww0 = sp0[0], ww1 = sp1[0];

  {
    const int p = tid;
    const float* kp = &kidx[p * CIn];
    float s0 = 0.f, s1 = 0.f;
#pragma unroll 16
    for (int ci = 0; ci < CIn; ++ci) {
      float kc = kp[ci];
      s0 += sqi[ci] * kc;
      s1 += sqi[CIn + ci] * kc;
    }
    float Iv = fmaxf(s0, 0.f) * ww0 + fmaxf(s1, 0.f) * ww1;
    int e = endbuf[p];
    if (!(e <= t && e >= 0)) Iv = NEGV;
    sI[p] = Iv;
  }
  __syncthreads();

  if (tid < 64) {
    float v0 = sI[tid], v1 = sI[tid + 64];
    for (int it = 0; it < TK; ++it) {
      float bv;
      int bi;
      if (v0 >= v1) { bv = v0; bi = tid; } else { bv = v1; bi = tid + 64; }
#pragma unroll
      for (int off = 32; off; off >>= 1) {
        float ov = __shfl_xor(bv, off, 64);
        int oi = __shfl_xor(bi, off, 64);
        if (ov > bv || (ov == bv && oi < bi)) { bv = ov; bi = oi; }
      }
      if (tid == 0) {
        sel[t * TK + it] = bi;
        selok[t * TK + it] = (bv > NEGV * 0.5f) ? 1 : 0;
      }
      if (bi == tid) v0 = -3.4e38f;
      if (bi == tid + 64) v1 = -3.4e38f;
    }
  }
}

// ---------------- attention v3 (split-bf16 packed output) ----------------
__global__ __launch_bounds__(256) void attn3_kernel(
    const float* __restrict__ q, const float* __restrict__ ksw,
    const float* __restrict__ kv, const float* __restrict__ kcsa,
    const float* __restrict__ ccsa, const int* __restrict__ sel,
    const int* __restrict__ selok, const float* __restrict__ sink,
    u16* __restrict__ atp) {
  const int tid = threadIdx.x;
  const int wid = tid >> 6, lane = tid & 63;
  const int g = lane >> 4;
  const int gl = lane & 15;
  const int pair = blockIdx.x * 4 + wid;
  const int t = pair >> 3, h = pair & 7;

  __shared__ float slog[4][164];
  __shared__ int s_sel[4][TK];
  __shared__ int s_ok[4][TK];

  if (lane < TK) {
    s_sel[wid][lane] = sel[t * TK + lane];
    s_ok[wid][lane] = selok[t * TK + lane];
  }
  const int hc = h * Cn + gl * 4;
  const float4 qf = *reinterpret_cast<const float4*>(&q[t * Dn + hc]);
  float* myslog = slog[wid];

#pragma unroll 4
  for (int pass = 0; pass < 32; ++pass) {
    int w = pass * 4 + g;
    int src = t + w - (NW - 1);
    int srcc = max(src, 0);
    float4 kk = *reinterpret_cast<const float4*>(&ksw[srcc * Dn + hc]);
    float acc = qf.x * kk.x + qf.y * kk.y + qf.z * kk.z + qf.w * kk.w;
#pragma unroll
    for (int off = 1; off < 16; off <<= 1) acc += __shfl_xor(acc, off, 64);
    if (gl == 0) myslog[TK + w] = (src >= 0) ? acc * 0.125f : NEGV;
  }
#pragma unroll 2
  for (int pass = 0; pass < 8; ++pass) {
    int s = pass * 4 + g;
    int se = s_sel[wid][s];
    float4 kk = *reinterpret_cast<const float4*>(&kcsa[se * Dn + hc]);
    float acc = qf.x * kk.x + qf.y * kk.y + qf.z * kk.z + qf.w * kk.w;
#pragma unroll
    for (int off = 1; off < 16; off <<= 1) acc += __shfl_xor(acc, off, 64);
    if (gl == 0) myslog[s] = s_ok[wid][s] ? acc * 0.125f : NEGV;
  }
  if (lane == 0) myslog[160] = sink[h];

  float x0 = myslog[lane];
  float x1 = myslog[lane + 64];
  float x2 = (lane < 33) ? myslog[lane + 128] : NEGV;
  float m = fmaxf(x0, fmaxf(x1, x2));
#pragma unroll
  for (int off = 32; off; off >>= 1) m = fmaxf(m, __shfl_xor(m, off, 64));
  float e0 = expf(x0 - m), e1 = expf(x1 - m);
  float e2 = (lane < 33) ? expf(x2 - m) : 0.f;
  float sden = e0 + e1 + e2;
#pragma unroll
  for (int off = 32; off; off >>= 1) sden += __shfl_xor(sden, off, 64);
  const float inv = 1.f / sden;
  myslog[lane] = e0 * inv;
  myslog[lane + 64] = e1 * inv;
  if (lane < 33) myslog[lane + 128] = e2 * inv;

  float4 acc = make_float4(0.f, 0.f, 0.f, 0.f);
#pragma unroll 4
  for (int pass = 0; pass < 32; ++pass) {
    int w = pass * 4 + g;
    int src = t + w - (NW - 1);
    int srcc = max(src, 0);
    float pv = myslog[TK + w];
    pv = (src >= 0) ? pv : 0.f;
    float4 vv = *reinterpret_cast<const float4*>(&kv[srcc * Dn + hc]);
    acc.x += pv * vv.x;
    acc.y += pv * vv.y;
    acc.z += pv * vv.z;
    acc.w += pv * vv.w;
  }
#pragma unroll 2
  for (int pass = 0; pass < 8; ++pass) {
    int s = pass * 4 + g;
    float pv = myslog[s];
    int se = s_sel[wid][s];
    float4 vv = *reinterpret_cast<const float4*>(&ccsa[se * Dn + hc]);
    acc.x += pv * vv.x;
    acc.y += pv * vv.y;
    acc.z += pv * vv.z;
    acc.w += pv * vv.w;
  }
  acc.x += __shfl_xor(acc.x, 16, 64);
  acc.y += __shfl_xor(acc.y, 16, 64);
  acc.z += __shfl_xor(acc.z, 16, 64);
  acc.w += __shfl_xor(acc.w, 16, 64);
  acc.x += __shfl_xor(acc.x, 32, 64);
  acc.y += __shfl_xor(acc.y, 32, 64);
  acc.z += __shfl_xor(acc.z, 32, 64);
  acc.w += __shfl_xor(acc.w, 32, 64);
  if (lane < 16) {
    float vals[4] = {acc.x, acc.y, acc.z, acc.w};
    int colb = h * Cn + lane * 4;
#pragma unroll
    for (int r = 0; r < 4; ++r) {
      int gc = colb + r;
      float v = vals[r];
      u16 hb = f2bf(v);
      u16 lb = f2bf(v - bf2f(hb));
      size_t idx = ((size_t)(gc >> 3) * 1024 + t) * 8 + (gc & 7);
      atp[idx] = hb;
      atp[idx + 524288] = lb;
    }
  }
}

// ---------------- host launcher ----------------
extern "C" void kernel_launch(void* const* d_in, const int* in_sizes, int n_in,
                              void* d_out, int out_size, void* d_ws,
                              size_t ws_size, hipStream_t stream) {
  const float* h = (const float*)d_in[0];
  const int* mask = (const int*)d_in[1];
  const int* tok = (const int*)d_in[2];
  const int* endp = (const int*)d_in[3];
  const float* W_dq = (const float*)d_in[5];
  const float* W_uq = (const float*)d_in[6];
  const float* W_csa_kv = (const float*)d_in[7];
  const float* W_csa_z = (const float*)d_in[8];
  const float* B_csa = (const float*)d_in[9];
  const float* W_idx_kv = (const float*)d_in[10];
  const float* W_idx_z = (const float*)d_in[11];
  const float* B_idx = (const float*)d_in[12];
  const float* W_iuq = (const float*)d_in[13];
  const float* W_w = (const float*)d_in[14];
  const float* W_swkv = (const float*)d_in[15];
  const float* qnw = (const float*)d_in[16];
  const float* knw = (const float*)d_in[17];
  const float* W_o = (const float*)d_in[18];
  const float* sink = (const float*)d_in[19];

  float* ws = (float*)d_ws;
  // arena with stream-ordered aliasing (floats offsets):
  u16* hA = (u16*)(ws + 0);          // 2 planes x 524288 u16; dead after K1
  float* qbuf = ws + 0;              // alias (written in K2)
  u16* qlP = (u16*)(ws + 524288);    // 2 planes x 262144 u16; dead after K2
  float* qib = ws + 524288;          // alias (written in K2idx)
  float* hckv = ws + 786432;         // dead after phrase
  u16* atP = (u16*)(ws + 786432);    // alias (written in attn)
  float* hcz = ws + 1310720;         // dead after phrase
  float* kswb = ws + 1310720;        // alias (written in rmsrope)
  float* kvb = ws + 1835008;
  float* hikv = ws + 2359296;
  float* hiz = ws + 2424832;
  float* q_lat = ws + 2490368;
  float* ccsa = ws + 2752512;
  float* kcsa = ws + 2818048;
  float* kidx = ws + 2883584;
  int* seli = (int*)(ws + 2891776);
  int* selok = (int*)(ws + 2924544);
  u16* pW = (u16*)(ws + 2957312);    // split-packed weights (hi+lo each)
  u16* pWdq = pW;                    // planes of 131072
  u16* pWckv = pWdq + 262144;        // planes of 262144
  u16* pWcz = pWckv + 524288;
  u16* pWsw = pWcz + 524288;
  u16* pWuq = pWsw + 524288;         // planes of 131072
  u16* pWo = pWuq + 262144;          // planes of 262144
  float* outp = (float*)d_out;

  // ---- pack all GEMM operands to split bf16 ----
  {
    PackJobs pj{};
    const float* srcs[7] = {h, W_dq, W_csa_kv, W_csa_z, W_swkv, W_uq, W_o};
    u16* dsts[7] = {hA, pWdq, pWckv, pWcz, pWsw, pWuq, pWo};
    int Ns[7] = {0, 256, 512, 512, 512, 512, 512};
    int logNs[7] = {0, 8, 9, 9, 9, 9, 9};
    int Ks[7] = {512, 512, 512, 512, 512, 256, 512};
    int isA[7] = {1, 0, 0, 0, 0, 0, 0};
    int pss[7] = {524288, 131072, 262144, 262144, 262144, 131072, 262144};
    int s = 0;
    for (int i = 0; i < 7; ++i) {
      pj.src[i] = srcs[i];
      pj.dst[i] = dsts[i];
      pj.N[i] = Ns[i];
      pj.logN[i] = logNs[i];
      pj.isA[i] = isA[i];
      pj.ps[i] = pss[i];
      pj.start[i] = s;
      s += isA[i] ? 1024 * (Ks[i] / 8) : (Ks[i] / 8) * Ns[i];
    }
    pj.start[7] = s;
    pack_all<<<(s + 255) / 256, 256, 0, stream>>>(pj);
  }

  auto normTile = [](const u16* pB, int N, int n0, float* C, int ldc, int bps) {
    TileDesc td{};
    td.Blo = pB + n0 * 8;
    td.Bhi = pB + (n0 + 64) * 8;
    td.ldNlo = td.ldNhi = N;
    td.Clo = C + n0;
    td.Chi = C + n0 + 64;
    td.ldClo = td.ldChi = ldc;
    td.mode = 0;
    td.bps = bps;
    return td;
  };

  // ---- K1: h @ {W_dq(mode2), W_csa_kv, W_csa_z, W_swkv} ----
  {
    GemmArgs ga{};
    int nt = 0;
    for (int n0 = 0; n0 < 256; n0 += 128) {
      TileDesc td = normTile(pWdq, 256, n0, q_lat, 256, 131072);
      td.mode = 2;
      td.Cp = qlP;
      td.cpps = 262144;
      td.n0 = n0;
      ga.d[nt++] = td;
    }
    for (int n0 = 0; n0 < 512; n0 += 128) ga.d[nt++] = normTile(pWckv, 512, n0, hckv, 512, 262144);
    for (int n0 = 0; n0 < 512; n0 += 128) ga.d[nt++] = normTile(pWcz, 512, n0, hcz, 512, 262144);
    for (int n0 = 0; n0 < 512; n0 += 128) ga.d[nt++] = normTile(pWsw, 512, n0, kvb, 512, 262144);
    gemm_bf16<<<dim3(nt, 8), 256, 0, stream>>>(hA, 16, 524288, ga);
  }
  // ---- K1-idx (fp32): h @ {W_idx_kv, W_idx_z} ----
  {
    SegParams sp;
    sp.nseg = 2;
    sp.B[0] = W_idx_kv; sp.C[0] = hikv; sp.width[0] = 64; sp.tstart[0] = 0;
    sp.B[1] = W_idx_z;  sp.C[1] = hiz;  sp.width[1] = 64; sp.tstart[1] = 1;
    sgemm_seg<<<dim3(2, 16), 256, 0, stream>>>(h, 512, sp);
  }
  // ---- K2: q_lat @ W_uq (split bf16) -> qbuf (aliases hA) ----
  {
    GemmArgs ga{};
    int nt = 0;
    for (int n0 = 0; n0 < 512; n0 += 128) ga.d[nt++] = normTile(pWuq, 512, n0, qbuf, 512, 131072);
    gemm_bf16<<<dim3(nt, 8), 256, 0, stream>>>(qlP, 8, 262144, ga);
  }
  // ---- K2-idx (fp32): q_lat @ W_iuq -> qib (aliases qlP) ----
  {
    SegParams sp;
    sp.nseg = 1;
    sp.B[0] = W_iuq; sp.C[0] = qib; sp.width[0] = 128; sp.tstart[0] = 0;
    sgemm_seg<<<dim3(2, 16), 256, 0, stream>>>(q_lat, 256, sp);
  }
  // ---- phrase aggregation ----
  phrase_kernel<<<Pn, 512, 0, stream>>>(mask, tok, endp, hckv, hcz, hikv, hiz,
                                        B_csa, B_idx, knw, ccsa, kcsa, kidx);
  // ---- q / k_sw rms+rope (kswb aliases hcz, dead after phrase) ----
  rmsrope_kernel<<<Tn, 512, 0, stream>>>(qbuf, kvb, kswb, qnw, knw);
  // ---- scores + top-32 ----
  score_topk_kernel<<<Tn, 128, 0, stream>>>(h, W_w, qib, kidx, endp, seli,
                                            selok);
  // ---- attention (writes split-packed atP, aliases hckv) ----
  attn3_kernel<<<dim3(Tn * Hn / 4), 256, 0, stream>>>(qbuf, kswb, kvb, kcsa,
                                                      ccsa, seli, selok, sink,
                                                      atP);
  // ---- K7: attno @ W_o (split bf16) -> out ----
  {
    GemmArgs ga{};
    int nt = 0;
    for (int n0 = 0; n0 < 512; n0 += 128) ga.d[nt++] = normTile(pWo, 512, n0, outp, 512, 262144);
    gemm_bf16<<<dim3(nt, 8), 256, 0, stream>>>(atP, 16, 524288, ga);
  }
  (void)in_sizes; (void)n_in; (void)out_size; (void)ws_size;
}

// Round 6
// 154.543 us; speedup vs baseline: 1.1955x; 1.1955x over previous
//
#include <hip/hip_runtime.h>
#include <cmath>

// ---------------- constants (match reference) ----------------
static constexpr int Tn = 1024, Dn = 512, Hn = 8, Cn = 64, DQn = 256,
                     NIn = 2, CIn = 64, TK = 32, LM = 16, NW = 128, Pn = 128;
#define NEGV (-1e30f)

typedef unsigned short u16;
typedef __bf16 bf16x8 __attribute__((ext_vector_type(8)));
typedef float f32x4 __attribute__((ext_vector_type(4)));

__device__ __forceinline__ u16 f2bf(float x) {
  unsigned u = __float_as_uint(x);
  return (u16)((u + 0x7fffu + ((u >> 16) & 1u)) >> 16);
}
__device__ __forceinline__ float bf2f(u16 b) {
  return __uint_as_float((unsigned)b << 16);
}

// ---------------- pack: fp32 -> split bf16 (hi+lo), k-grouped-by-8 ----------
struct PackJobs {
  const float* src[7];
  u16* dst[7];
  int start[8];
  int N[7];
  int logN[7];
  int isA[7];
  int ps[7];  // plane size in u16 elements
};

__global__ __launch_bounds__(256) void pack_all(PackJobs pj) {
  int i = blockIdx.x * 256 + threadIdx.x;
  if (i >= pj.start[7]) return;
  int j = 0;
  while (i >= pj.start[j + 1]) ++j;
  int local = i - pj.start[j];
  const float* s = pj.src[j];
  u16* dh = pj.dst[j];
  u16* dl = dh + pj.ps[j];
  float x[8];
  if (pj.isA[j]) {
    int kg = local & 63;  // K=512 -> 64 kgroups
    int m = local >> 6;
    const float4* p = reinterpret_cast<const float4*>(s + (size_t)m * 512 + kg * 8);
    float4 a = p[0], b = p[1];
    x[0] = a.x; x[1] = a.y; x[2] = a.z; x[3] = a.w;
    x[4] = b.x; x[5] = b.y; x[6] = b.z; x[7] = b.w;
    union { u16 u[8]; int4 v; } oh, ol;
#pragma unroll
    for (int e = 0; e < 8; ++e) {
      u16 hb = f2bf(x[e]);
      oh.u[e] = hb;
      ol.u[e] = f2bf(x[e] - bf2f(hb));
    }
    size_t idx = ((size_t)kg * 1024 + m) * 8;
    *reinterpret_cast<int4*>(dh + idx) = oh.v;
    *reinterpret_cast<int4*>(dl + idx) = ol.v;
  } else {
    int N = pj.N[j];
    int n = local & (N - 1);
    int kg = local >> pj.logN[j];
#pragma unroll
    for (int e = 0; e < 8; ++e) x[e] = s[(size_t)(kg * 8 + e) * N + n];
    union { u16 u[8]; int4 v; } oh, ol;
#pragma unroll
    for (int e = 0; e < 8; ++e) {
      u16 hb = f2bf(x[e]);
      oh.u[e] = hb;
      ol.u[e] = f2bf(x[e] - bf2f(hb));
    }
    size_t idx = ((size_t)kg * N + n) * 8;
    *reinterpret_cast<int4*>(dh + idx) = oh.v;
    *reinterpret_cast<int4*>(dl + idx) = ol.v;
  }
}

// ---------------- split-bf16 MFMA GEMM ----------------
// 128x128 tile, 4 waves (64x64 quadrant each, 4x4 frags of 16x16x32), BK=32,
// double-buffered LDS, hi/lo planes, 3 MFMA per fragment pair.
struct TileDesc {
  const u16* Blo;
  const u16* Bhi;
  float* Clo;
  float* Chi;
  u16* Cp;
  int ldNlo, ldNhi, ldClo, ldChi, mode, n0, bps, cpps;
};
struct GemmArgs {
  TileDesc d[15];
};

#define GLD16(gp, lp)                                                     \
  __builtin_amdgcn_global_load_lds(                                      \
      (const __attribute__((address_space(1))) unsigned int*)(gp),       \
      (__attribute__((address_space(3))) unsigned int*)(lp), 16, 0, 0)

__global__ __launch_bounds__(256) void gemm_bf16(const u16* __restrict__ Ap,
                                                 int NK, int aps, GemmArgs ga) {
  const int ct = blockIdx.x, rt = blockIdx.y;
  const TileDesc d = ga.d[ct];
  const int m0 = rt * 128;
  __shared__ __align__(16) u16 lA[2][2][4][128][8];
  __shared__ __align__(16) u16 lB[2][2][4][128][8];
  const int tid = threadIdx.x;
  const int w = tid >> 6, lane = tid & 63;
  const int wm = w >> 1, wn = w & 1;

  f32x4 acc[4][4];
#pragma unroll
  for (int a = 0; a < 4; ++a)
#pragma unroll
    for (int b = 0; b < 4; ++b)
#pragma unroll
      for (int r = 0; r < 4; ++r) acc[a][b][r] = 0.f;

  auto stage = [&](int buf, int kg) {
    GLD16(Ap + ((size_t)kg * 1024 + m0 + lane) * 8, &lA[buf][0][w][0][0]);
    GLD16(Ap + ((size_t)kg * 1024 + m0 + 64 + lane) * 8, &lA[buf][0][w][64][0]);
    GLD16(Ap + aps + ((size_t)kg * 1024 + m0 + lane) * 8, &lA[buf][1][w][0][0]);
    GLD16(Ap + aps + ((size_t)kg * 1024 + m0 + 64 + lane) * 8, &lA[buf][1][w][64][0]);
    GLD16(d.Blo + ((size_t)kg * d.ldNlo + lane) * 8, &lB[buf][0][w][0][0]);
    GLD16(d.Bhi + ((size_t)kg * d.ldNhi + lane) * 8, &lB[buf][0][w][64][0]);
    GLD16(d.Blo + d.bps + ((size_t)kg * d.ldNlo + lane) * 8, &lB[buf][1][w][0][0]);
    GLD16(d.Bhi + d.bps + ((size_t)kg * d.ldNhi + lane) * 8, &lB[buf][1][w][64][0]);
  };

  stage(0, w);  // kgroup w of K-step 0
  const int kq = lane >> 4, fr = lane & 15;
  for (int ks = 0; ks < NK; ++ks) {
    __syncthreads();  // drains vmcnt -> buf[ks&1] staged; syncs prev compute
    if (ks + 1 < NK) stage((ks + 1) & 1, (ks + 1) * 4 + w);
    const int cb = ks & 1;
    bf16x8 aFh[4], aFl[4], bFh[4], bFl[4];
#pragma unroll
    for (int f = 0; f < 4; ++f) {
      aFh[f] = *reinterpret_cast<const bf16x8*>(&lA[cb][0][kq][wm * 64 + f * 16 + fr][0]);
      aFl[f] = *reinterpret_cast<const bf16x8*>(&lA[cb][1][kq][wm * 64 + f * 16 + fr][0]);
      bFh[f] = *reinterpret_cast<const bf16x8*>(&lB[cb][0][kq][wn * 64 + f * 16 + fr][0]);
      bFl[f] = *reinterpret_cast<const bf16x8*>(&lB[cb][1][kq][wn * 64 + f * 16 + fr][0]);
    }
#pragma unroll
    for (int fm = 0; fm < 4; ++fm)
#pragma unroll
      for (int fn = 0; fn < 4; ++fn) {
        acc[fm][fn] = __builtin_amdgcn_mfma_f32_16x16x32_bf16(aFh[fm], bFh[fn],
                                                              acc[fm][fn], 0, 0, 0);
        acc[fm][fn] = __builtin_amdgcn_mfma_f32_16x16x32_bf16(aFl[fm], bFh[fn],
                                                              acc[fm][fn], 0, 0, 0);
        acc[fm][fn] = __builtin_amdgcn_mfma_f32_16x16x32_bf16(aFh[fm], bFl[fn],
                                                              acc[fm][fn], 0, 0, 0);
      }
  }
  // epilogue: row = m0+wm*64+fm*16+(lane>>4)*4+r, col = wn*64+fn*16+(lane&15)
  float* Cb = (wn == 0) ? d.Clo : d.Chi;
  const int ldc = (wn == 0) ? d.ldClo : d.ldChi;
  if (d.mode != 1) {
#pragma unroll
    for (int fm = 0; fm < 4; ++fm)
#pragma unroll
      for (int fn = 0; fn < 4; ++fn)
#pragma unroll
        for (int r = 0; r < 4; ++r) {
          int row = m0 + wm * 64 + fm * 16 + (lane >> 4) * 4 + r;
          int cl = fn * 16 + fr;
          Cb[(size_t)row * ldc + cl] = acc[fm][fn][r];
        }
  }
  if (d.mode >= 1) {
#pragma unroll
    for (int fm = 0; fm < 4; ++fm)
#pragma unroll
      for (int fn = 0; fn < 4; ++fn)
#pragma unroll
        for (int r = 0; r < 4; ++r) {
          int row = m0 + wm * 64 + fm * 16 + (lane >> 4) * 4 + r;
          int gc = d.n0 + wn * 64 + fn * 16 + fr;
          float v = acc[fm][fn][r];
          u16 hb = f2bf(v);
          u16 lb = f2bf(v - bf2f(hb));
          size_t idx = ((size_t)(gc >> 3) * 1024 + row) * 8 + (gc & 7);
          d.Cp[idx] = hb;
          d.Cp[idx + d.cpps] = lb;
        }
  }
}

// ---------------- fused fp32 index-path GEMMs (row-parallel) ----------------
// One block per token t, 256 threads. Stages h[t] (512f) + q_lat[t] (256f) in
// LDS. Wave 0: hikv (64 dots K=512), wave 1: hiz (64 dots K=512),
// waves 2-3: q_i (128 dots K=256). All W reads lane-coalesced.
__global__ __launch_bounds__(256) void idx_kernel(
    const float* __restrict__ h, const float* __restrict__ q_lat,
    const float* __restrict__ Wikv, const float* __restrict__ Wiz,
    const float* __restrict__ Wiuq, float* __restrict__ hikv,
    float* __restrict__ hiz, float* __restrict__ qib) {
  const int t = blockIdx.x;
  const int tid = threadIdx.x;
  __shared__ float hs[Dn];
  __shared__ float ql[DQn];
  hs[tid] = h[(size_t)t * Dn + tid];
  hs[tid + 256] = h[(size_t)t * Dn + tid + 256];
  ql[tid & 255] = q_lat[(size_t)t * DQn + (tid & 255)];
  __syncthreads();
  if (tid < 128) {
    const float* Wm = (tid < 64) ? Wikv : Wiz;
    const int ci = tid & 63;
    float a0 = 0.f, a1 = 0.f, a2 = 0.f, a3 = 0.f;
#pragma unroll 4
    for (int k = 0; k < Dn; k += 4) {
      a0 += hs[k + 0] * Wm[(k + 0) * CIn + ci];
      a1 += hs[k + 1] * Wm[(k + 1) * CIn + ci];
      a2 += hs[k + 2] * Wm[(k + 2) * CIn + ci];
      a3 += hs[k + 3] * Wm[(k + 3) * CIn + ci];
    }
    float acc = (a0 + a1) + (a2 + a3);
    if (tid < 64)
      hikv[(size_t)t * CIn + ci] = acc;
    else
      hiz[(size_t)t * CIn + ci] = acc;
  } else {
    const int jj = tid - 128;  // 0..127
    float a0 = 0.f, a1 = 0.f, a2 = 0.f, a3 = 0.f;
#pragma unroll 4
    for (int k = 0; k < DQn; k += 4) {
      a0 += ql[k + 0] * Wiuq[(k + 0) * 128 + jj];
      a1 += ql[k + 1] * Wiuq[(k + 1) * 128 + jj];
      a2 += ql[k + 2] * Wiuq[(k + 2) * 128 + jj];
      a3 += ql[k + 3] * Wiuq[(k + 3) * 128 + jj];
    }
    qib[(size_t)t * 128 + jj] = (a0 + a1) + (a2 + a3);
  }
}

// ---------------- phrase aggregation ----------------
__global__ __launch_bounds__(512) void phrase_kernel(
    const int* __restrict__ maskbuf, const int* __restrict__ tokbuf,
    const int* __restrict__ endbuf, const float* __restrict__ hckv,
    const float* __restrict__ hcz, const float* __restrict__ hikv,
    const float* __restrict__ hiz, const float* __restrict__ Bcsa,
    const float* __restrict__ Bidx, const float* __restrict__ knw,
    float* __restrict__ ccsa, float* __restrict__ kcsa,
    float* __restrict__ kidx) {
  const int p = blockIdx.x;
  const int tid = threadIdx.x;
  __shared__ int s_bytemode;
  __shared__ int s_tok[LM];
  __shared__ int s_m[LM];
  __shared__ int s_pos, s_anyv;

  if (tid == 0) s_bytemode = 0;
  __syncthreads();
  {
    unsigned w = ((const unsigned*)maskbuf)[tid];  // tid in [0,512)
    if (w > 1u) atomicOr(&s_bytemode, 1);
  }
  __syncthreads();
  const int bytemode = s_bytemode;
  if (tid < LM) {
    int mv;
    if (bytemode)
      mv = ((const unsigned char*)maskbuf)[p * LM + tid] != 0;
    else
      mv = maskbuf[p * LM + tid] != 0;
    s_m[tid] = mv;
    s_tok[tid] = tokbuf[p * LM + tid];
  }
  if (tid == 0) {
    int e = endbuf[p];
    s_pos = min(max(e, 0), Tn - 1);
  }
  __syncthreads();
  if (tid == 0) {
    int any = 0;
    for (int l = 0; l < LM; ++l) any |= s_m[l];
    s_anyv = any;
  }
  __syncthreads();
  const int anyv = s_anyv;
  const int pos = s_pos;
  const int c = tid & 63;
  const float fr = (float)pos * powf(10000.0f, -(float)(c & 31) / 32.0f);
  const float cv = cosf(fr), sv = sinf(fr);
  const float sgn = (c < 32) ? -1.f : 1.f;

  {
    float z[LM];
    float zmax = NEGV;
#pragma unroll
    for (int l = 0; l < LM; ++l) {
      float zv = hcz[s_tok[l] * Dn + tid] + Bcsa[l * (Hn * Cn) + tid];
      zv = s_m[l] ? zv : NEGV;
      z[l] = zv;
      zmax = fmaxf(zmax, zv);
    }
    float den = 0.f, num = 0.f;
#pragma unroll
    for (int l = 0; l < LM; ++l) {
      float e = expf(z[l] - zmax);
      den += e;
      num += e * hckv[s_tok[l] * Dn + tid];
    }
    float cc = anyv ? (num / den) : 0.f;
    ccsa[p * (Hn * Cn) + tid] = cc;

    float ss = cc * cc;
#pragma unroll
    for (int off = 32; off; off >>= 1) ss += __shfl_xor(ss, off, 64);
    float kn = cc * rsqrtf(ss / (float)Cn + 1e-6f) * knw[c];
    float pr = __shfl_xor(kn, 32, 64);
    kcsa[p * (Hn * Cn) + tid] = kn * cv + sgn * pr * sv;
  }

  if (tid < CIn) {
    float zk[LM];
    float zm = NEGV;
#pragma unroll
    for (int l = 0; l < LM; ++l) {
      float zv = hiz[s_tok[l] * CIn + tid] + Bidx[l * CIn + tid];
      zv = s_m[l] ? zv : NEGV;
      zk[l] = zv;
      zm = fmaxf(zm, zv);
    }
    float dk = 0.f, nk = 0.f;
#pragma unroll
    for (int l = 0; l < LM; ++l) {
      float e = expf(zk[l] - zm);
      dk += e;
      nk += e * hikv[s_tok[l] * CIn + tid];
    }
    float ki = anyv ? (nk / dk) : 0.f;
    float pr = __shfl_xor(ki, 32, 64);
    kidx[p * CIn + tid] = ki * cv + sgn * pr * sv;
  }
}

// ---------------- RMS+RoPE for q (in place) and k_sw ----------------
__global__ __launch_bounds__(512) void rmsrope_kernel(
    float* __restrict__ q, const float* __restrict__ kv,
    float* __restrict__ ksw, const float* __restrict__ qnw,
    const float* __restrict__ knw) {
  const int t = blockIdx.x;
  const int tid = threadIdx.x;
  const int c = tid & 63;
  const float fr = (float)t * powf(10000.0f, -(float)(c & 31) / 32.0f);
  const float cv = cosf(fr), sv = sinf(fr);
  const float sgn = (c < 32) ? -1.f : 1.f;
  {
    float x = q[t * Dn + tid];
    float ss = x * x;
#pragma unroll
    for (int off = 32; off; off >>= 1) ss += __shfl_xor(ss, off, 64);
    float xr = x * rsqrtf(ss / (float)Cn + 1e-6f) * qnw[c];
    float pr = __shfl_xor(xr, 32, 64);
    q[t * Dn + tid] = xr * cv + sgn * pr * sv;
  }
  {
    float y = kv[t * Dn + tid];
    float ss = y * y;
#pragma unroll
    for (int off = 32; off; off >>= 1) ss += __shfl_xor(ss, off, 64);
    float yr = y * rsqrtf(ss / (float)Cn + 1e-6f) * knw[c];
    float pr = __shfl_xor(yr, 32, 64);
    ksw[t * Dn + tid] = yr * cv + sgn * pr * sv;
  }
}

// ---------------- phrase scores + top-32 (all fp32) ----------------
__global__ __launch_bounds__(128) void score_topk_kernel(
    const float* __restrict__ hbuf, const float* __restrict__ Ww,
    const float* __restrict__ qi, const float* __restrict__ kidx,
    const int* __restrict__ endbuf, int* __restrict__ sel,
    int* __restrict__ selok) {
  const int t = blockIdx.x;
  const int tid = threadIdx.x;
  __shared__ float sqi[NIn * CIn];
  __shared__ float sI[Pn];
  __shared__ float sp0[128], sp1[128];

  sqi[tid] = qi[t * (NIn * CIn) + tid];
  float p0 = 0.f, p1 = 0.f;
#pragma unroll
  for (int e4 = 0; e4 < 4; ++e4) {
    int e = tid * 4 + e4;
    float hv = hbuf[t * Dn + e];
    p0 += hv * Ww[e * NIn + 0];
    p1 += hv * Ww[e * NIn + 1];
  }
  sp0[tid] = p0;
  sp1[tid] = p1;
  __syncthreads();
  for (int srd = 64; srd; srd >>= 1) {
    if (tid < srd) {
      sp0[tid] += sp0[tid + srd];
      sp1[tid] += sp1[tid + srd];
    }
    __syncthreads();
  }
  const float ww0 = sp0[0], ww1 = sp1[0];

  {
    const int p = tid;
    const float* kp = &kidx[p * CIn];
    float s0 = 0.f, s1 = 0.f;
#pragma unroll 16
    for (int ci = 0; ci < CIn; ++ci) {
      float kc = kp[ci];
      s0 += sqi[ci] * kc;
      s1 += sqi[CIn + ci] * kc;
    }
    float Iv = fmaxf(s0, 0.f) * ww0 + fmaxf(s1, 0.f) * ww1;
    int e = endbuf[p];
    if (!(e <= t && e >= 0)) Iv = NEGV;
    sI[p] = Iv;
  }
  __syncthreads();

  if (tid < 64) {
    float v0 = sI[tid], v1 = sI[tid + 64];
    for (int it = 0; it < TK; ++it) {
      float bv;
      int bi;
      if (v0 >= v1) { bv = v0; bi = tid; } else { bv = v1; bi = tid + 64; }
#pragma unroll
      for (int off = 32; off; off >>= 1) {
        float ov = __shfl_xor(bv, off, 64);
        int oi = __shfl_xor(bi, off, 64);
        if (ov > bv || (ov == bv && oi < bi)) { bv = ov; bi = oi; }
      }
      if (tid == 0) {
        sel[t * TK + it] = bi;
        selok[t * TK + it] = (bv > NEGV * 0.5f) ? 1 : 0;
      }
      if (bi == tid) v0 = -3.4e38f;
      if (bi == tid + 64) v1 = -3.4e38f;
    }
  }
}

// ---------------- attention v3 (split-bf16 packed output) ----------------
__global__ __launch_bounds__(256) void attn3_kernel(
    const float* __restrict__ q, const float* __restrict__ ksw,
    const float* __restrict__ kv, const float* __restrict__ kcsa,
    const float* __restrict__ ccsa, const int* __restrict__ sel,
    const int* __restrict__ selok, const float* __restrict__ sink,
    u16* __restrict__ atp) {
  const int tid = threadIdx.x;
  const int wid = tid >> 6, lane = tid & 63;
  const int g = lane >> 4;
  const int gl = lane & 15;
  const int pair = blockIdx.x * 4 + wid;
  const int t = pair >> 3, h = pair & 7;

  __shared__ float slog[4][164];
  __shared__ int s_sel[4][TK];
  __shared__ int s_ok[4][TK];

  if (lane < TK) {
    s_sel[wid][lane] = sel[t * TK + lane];
    s_ok[wid][lane] = selok[t * TK + lane];
  }
  const int hc = h * Cn + gl * 4;
  const float4 qf = *reinterpret_cast<const float4*>(&q[t * Dn + hc]);
  float* myslog = slog[wid];

#pragma unroll 4
  for (int pass = 0; pass < 32; ++pass) {
    int w = pass * 4 + g;
    int src = t + w - (NW - 1);
    int srcc = max(src, 0);
    float4 kk = *reinterpret_cast<const float4*>(&ksw[srcc * Dn + hc]);
    float acc = qf.x * kk.x + qf.y * kk.y + qf.z * kk.z + qf.w * kk.w;
#pragma unroll
    for (int off = 1; off < 16; off <<= 1) acc += __shfl_xor(acc, off, 64);
    if (gl == 0) myslog[TK + w] = (src >= 0) ? acc * 0.125f : NEGV;
  }
#pragma unroll 2
  for (int pass = 0; pass < 8; ++pass) {
    int s = pass * 4 + g;
    int se = s_sel[wid][s];
    float4 kk = *reinterpret_cast<const float4*>(&kcsa[se * Dn + hc]);
    float acc = qf.x * kk.x + qf.y * kk.y + qf.z * kk.z + qf.w * kk.w;
#pragma unroll
    for (int off = 1; off < 16; off <<= 1) acc += __shfl_xor(acc, off, 64);
    if (gl == 0) myslog[s] = s_ok[wid][s] ? acc * 0.125f : NEGV;
  }
  if (lane == 0) myslog[160] = sink[h];

  float x0 = myslog[lane];
  float x1 = myslog[lane + 64];
  float x2 = (lane < 33) ? myslog[lane + 128] : NEGV;
  float m = fmaxf(x0, fmaxf(x1, x2));
#pragma unroll
  for (int off = 32; off; off >>= 1) m = fmaxf(m, __shfl_xor(m, off, 64));
  float e0 = expf(x0 - m), e1 = expf(x1 - m);
  float e2 = (lane < 33) ? expf(x2 - m) : 0.f;
  float sden = e0 + e1 + e2;
#pragma unroll
  for (int off = 32; off; off >>= 1) sden += __shfl_xor(sden, off, 64);
  const float inv = 1.f / sden;
  myslog[lane] = e0 * inv;
  myslog[lane + 64] = e1 * inv;
  if (lane < 33) myslog[lane + 128] = e2 * inv;

  float4 acc = make_float4(0.f, 0.f, 0.f, 0.f);
#pragma unroll 4
  for (int pass = 0; pass < 32; ++pass) {
    int w = pass * 4 + g;
    int src = t + w - (NW - 1);
    int srcc = max(src, 0);
    float pv = myslog[TK + w];
    pv = (src >= 0) ? pv : 0.f;
    float4 vv = *reinterpret_cast<const float4*>(&kv[srcc * Dn + hc]);
    acc.x += pv * vv.x;
    acc.y += pv * vv.y;
    acc.z += pv * vv.z;
    acc.w += pv * vv.w;
  }
#pragma unroll 2
  for (int pass = 0; pass < 8; ++pass) {
    int s = pass * 4 + g;
    float pv = myslog[s];
    int se = s_sel[wid][s];
    float4 vv = *reinterpret_cast<const float4*>(&ccsa[se * Dn + hc]);
    acc.x += pv * vv.x;
    acc.y += pv * vv.y;
    acc.z += pv * vv.z;
    acc.w += pv * vv.w;
  }
  acc.x += __shfl_xor(acc.x, 16, 64);
  acc.y += __shfl_xor(acc.y, 16, 64);
  acc.z += __shfl_xor(acc.z, 16, 64);
  acc.w += __shfl_xor(acc.w, 16, 64);
  acc.x += __shfl_xor(acc.x, 32, 64);
  acc.y += __shfl_xor(acc.y, 32, 64);
  acc.z += __shfl_xor(acc.z, 32, 64);
  acc.w += __shfl_xor(acc.w, 32, 64);
  if (lane < 16) {
    float vals[4] = {acc.x, acc.y, acc.z, acc.w};
    int colb = h * Cn + lane * 4;
#pragma unroll
    for (int r = 0; r < 4; ++r) {
      int gc = colb + r;
      float v = vals[r];
      u16 hb = f2bf(v);
      u16 lb = f2bf(v - bf2f(hb));
      size_t idx = ((size_t)(gc >> 3) * 1024 + t) * 8 + (gc & 7);
      atp[idx] = hb;
      atp[idx + 524288] = lb;
    }
  }
}

// ---------------- host launcher ----------------
extern "C" void kernel_launch(void* const* d_in, const int* in_sizes, int n_in,
                              void* d_out, int out_size, void* d_ws,
                              size_t ws_size, hipStream_t stream) {
  const float* h = (const float*)d_in[0];
  const int* mask = (const int*)d_in[1];
  const int* tok = (const int*)d_in[2];
  const int* endp = (const int*)d_in[3];
  const float* W_dq = (const float*)d_in[5];
  const float* W_uq = (const float*)d_in[6];
  const float* W_csa_kv = (const float*)d_in[7];
  const float* W_csa_z = (const float*)d_in[8];
  const float* B_csa = (const float*)d_in[9];
  const float* W_idx_kv = (const float*)d_in[10];
  const float* W_idx_z = (const float*)d_in[11];
  const float* B_idx = (const float*)d_in[12];
  const float* W_iuq = (const float*)d_in[13];
  const float* W_w = (const float*)d_in[14];
  const float* W_swkv = (const float*)d_in[15];
  const float* qnw = (const float*)d_in[16];
  const float* knw = (const float*)d_in[17];
  const float* W_o = (const float*)d_in[18];
  const float* sink = (const float*)d_in[19];

  float* ws = (float*)d_ws;
  // arena with stream-ordered aliasing (float offsets):
  u16* hA = (u16*)(ws + 0);          // 2 planes x 524288 u16; dead after K2... (A of K1)
  float* qbuf = ws + 0;              // alias (written in K2)
  u16* qlP = (u16*)(ws + 524288);    // 2 planes x 262144 u16; A of K2
  float* hckv = ws + 786432;         // dead after phrase
  u16* atP = (u16*)(ws + 786432);    // alias (written in attn)
  float* hcz = ws + 1310720;         // dead after phrase
  float* kswb = ws + 1310720;        // alias (written in rmsrope)
  float* kvb = ws + 1835008;
  float* hikv = ws + 2359296;
  float* hiz = ws + 2424832;
  float* q_lat = ws + 2490368;
  float* ccsa = ws + 2752512;
  float* kcsa = ws + 2818048;
  float* kidx = ws + 2883584;
  int* seli = (int*)(ws + 2891776);
  int* selok = (int*)(ws + 2924544);
  u16* pW = (u16*)(ws + 2957312);    // split-packed weights (hi+lo each)
  u16* pWdq = pW;                    // planes of 131072
  u16* pWckv = pWdq + 262144;        // planes of 262144
  u16* pWcz = pWckv + 524288;
  u16* pWsw = pWcz + 524288;
  u16* pWuq = pWsw + 524288;         // planes of 131072
  u16* pWo = pWuq + 262144;          // planes of 262144
  float* qib = ws + 4268032;         // 1024*128 fp32 (own space)
  float* outp = (float*)d_out;

  // ---- pack all GEMM operands to split bf16 ----
  {
    PackJobs pj{};
    const float* srcs[7] = {h, W_dq, W_csa_kv, W_csa_z, W_swkv, W_uq, W_o};
    u16* dsts[7] = {hA, pWdq, pWckv, pWcz, pWsw, pWuq, pWo};
    int Ns[7] = {0, 256, 512, 512, 512, 512, 512};
    int logNs[7] = {0, 8, 9, 9, 9, 9, 9};
    int Ks[7] = {512, 512, 512, 512, 512, 256, 512};
    int isA[7] = {1, 0, 0, 0, 0, 0, 0};
    int pss[7] = {524288, 131072, 262144, 262144, 262144, 131072, 262144};
    int s = 0;
    for (int i = 0; i < 7; ++i) {
      pj.src[i] = srcs[i];
      pj.dst[i] = dsts[i];
      pj.N[i] = Ns[i];
      pj.logN[i] = logNs[i];
      pj.isA[i] = isA[i];
      pj.ps[i] = pss[i];
      pj.start[i] = s;
      s += isA[i] ? 1024 * (Ks[i] / 8) : (Ks[i] / 8) * Ns[i];
    }
    pj.start[7] = s;
    pack_all<<<(s + 255) / 256, 256, 0, stream>>>(pj);
  }

  auto normTile = [](const u16* pB, int N, int n0, float* C, int ldc, int bps) {
    TileDesc td{};
    td.Blo = pB + n0 * 8;
    td.Bhi = pB + (n0 + 64) * 8;
    td.ldNlo = td.ldNhi = N;
    td.Clo = C + n0;
    td.Chi = C + n0 + 64;
    td.ldClo = td.ldChi = ldc;
    td.mode = 0;
    td.bps = bps;
    return td;
  };

  // ---- K1: h @ {W_dq(mode2), W_csa_kv, W_csa_z, W_swkv} ----
  {
    GemmArgs ga{};
    int nt = 0;
    for (int n0 = 0; n0 < 256; n0 += 128) {
      TileDesc td = normTile(pWdq, 256, n0, q_lat, 256, 131072);
      td.mode = 2;
      td.Cp = qlP;
      td.cpps = 262144;
      td.n0 = n0;
      ga.d[nt++] = td;
    }
    for (int n0 = 0; n0 < 512; n0 += 128) ga.d[nt++] = normTile(pWckv, 512, n0, hckv, 512, 262144);
    for (int n0 = 0; n0 < 512; n0 += 128) ga.d[nt++] = normTile(pWcz, 512, n0, hcz, 512, 262144);
    for (int n0 = 0; n0 < 512; n0 += 128) ga.d[nt++] = normTile(pWsw, 512, n0, kvb, 512, 262144);
    gemm_bf16<<<dim3(nt, 8), 256, 0, stream>>>(hA, 16, 524288, ga);
  }
  // ---- K2: q_lat @ W_uq (split bf16) -> qbuf (aliases hA, dead after K1... A of K2 is qlP) ----
  {
    GemmArgs ga{};
    int nt = 0;
    for (int n0 = 0; n0 < 512; n0 += 128) ga.d[nt++] = normTile(pWuq, 512, n0, qbuf, 512, 131072);
    gemm_bf16<<<dim3(nt, 8), 256, 0, stream>>>(qlP, 8, 262144, ga);
  }
  // ---- fused fp32 idx-path GEMMs: hikv, hiz, q_i ----
  idx_kernel<<<Tn, 256, 0, stream>>>(h, q_lat, W_idx_kv, W_idx_z, W_iuq, hikv,
                                     hiz, qib);
  // ---- phrase aggregation ----
  phrase_kernel<<<Pn, 512, 0, stream>>>(mask, tok, endp, hckv, hcz, hikv, hiz,
                                        B_csa, B_idx, knw, ccsa, kcsa, kidx);
  // ---- q / k_sw rms+rope (kswb aliases hcz, dead after phrase) ----
  rmsrope_kernel<<<Tn, 512, 0, stream>>>(qbuf, kvb, kswb, qnw, knw);
  // ---- scores + top-32 ----
  score_topk_kernel<<<Tn, 128, 0, stream>>>(h, W_w, qib, kidx, endp, seli,
                                            selok);
  // ---- attention (writes split-packed atP, aliases hckv) ----
  attn3_kernel<<<dim3(Tn * Hn / 4), 256, 0, stream>>>(qbuf, kswb, kvb, kcsa,
                                                      ccsa, seli, selok, sink,
                                                      atP);
  // ---- K7: attno @ W_o (split bf16) -> out ----
  {
    GemmArgs ga{};
    int nt = 0;
    for (int n0 = 0; n0 < 512; n0 += 128) ga.d[nt++] = normTile(pWo, 512, n0, outp, 512, 262144);
    gemm_bf16<<<dim3(nt, 8), 256, 0, stream>>>(atP, 16, 524288, ga);
  }
  (void)in_sizes; (void)n_in; (void)out_size; (void)ws_size;
}

// Round 7
// 151.051 us; speedup vs baseline: 1.2231x; 1.0231x over previous
//
#include <hip/hip_runtime.h>
#include <cmath>

// ---------------- constants (match reference) ----------------
static constexpr int Tn = 1024, Dn = 512, Hn = 8, Cn = 64, DQn = 256,
                     NIn = 2, CIn = 64, TK = 32, LM = 16, NW = 128, Pn = 128;
#define NEGV (-1e30f)

typedef unsigned short u16;
typedef __bf16 bf16x8 __attribute__((ext_vector_type(8)));
typedef float f32x4 __attribute__((ext_vector_type(4)));

__device__ __forceinline__ u16 f2bf(float x) {
  unsigned u = __float_as_uint(x);
  return (u16)((u + 0x7fffu + ((u >> 16) & 1u)) >> 16);
}
__device__ __forceinline__ float bf2f(u16 b) {
  return __uint_as_float((unsigned)b << 16);
}

// ---------------- pack: fp32 -> split bf16 (hi+lo), k-grouped-by-8 ----------
struct PackJobs {
  const float* src[7];
  u16* dst[7];
  int start[8];
  int N[7];
  int logN[7];
  int isA[7];
  int ps[7];  // plane size in u16 elements
};

__global__ __launch_bounds__(256) void pack_all(PackJobs pj) {
  int i = blockIdx.x * 256 + threadIdx.x;
  if (i >= pj.start[7]) return;
  int j = 0;
  while (i >= pj.start[j + 1]) ++j;
  int local = i - pj.start[j];
  const float* s = pj.src[j];
  u16* dh = pj.dst[j];
  u16* dl = dh + pj.ps[j];
  float x[8];
  size_t idx;
  if (pj.isA[j]) {
    // m-major mapping: coalesced writes, scattered (read-combined) loads
    int m = local & 1023;
    int kg = local >> 10;
    const float4* p = reinterpret_cast<const float4*>(s + (size_t)m * 512 + kg * 8);
    float4 a = p[0], b = p[1];
    x[0] = a.x; x[1] = a.y; x[2] = a.z; x[3] = a.w;
    x[4] = b.x; x[5] = b.y; x[6] = b.z; x[7] = b.w;
    idx = ((size_t)kg * 1024 + m) * 8;
  } else {
    int N = pj.N[j];
    int n = local & (N - 1);
    int kg = local >> pj.logN[j];
#pragma unroll
    for (int e = 0; e < 8; ++e) x[e] = s[(size_t)(kg * 8 + e) * N + n];
    idx = ((size_t)kg * N + n) * 8;
  }
  union { u16 u[8]; int4 v; } oh, ol;
#pragma unroll
  for (int e = 0; e < 8; ++e) {
    u16 hb = f2bf(x[e]);
    oh.u[e] = hb;
    ol.u[e] = f2bf(x[e] - bf2f(hb));
  }
  *reinterpret_cast<int4*>(dh + idx) = oh.v;
  *reinterpret_cast<int4*>(dl + idx) = ol.v;
}

// ---------------- split-bf16 MFMA GEMM ----------------
struct TileDesc {
  const u16* Blo;
  const u16* Bhi;
  float* Clo;
  float* Chi;
  u16* Cp;
  int ldNlo, ldNhi, ldClo, ldChi, mode, n0, bps, cpps;
};
struct GemmArgs {
  TileDesc d[15];
};

#define GLD16(gp, lp)                                                     \
  __builtin_amdgcn_global_load_lds(                                      \
      (const __attribute__((address_space(1))) unsigned int*)(gp),       \
      (__attribute__((address_space(3))) unsigned int*)(lp), 16, 0, 0)

__global__ __launch_bounds__(256) void gemm_bf16(const u16* __restrict__ Ap,
                                                 int NK, int aps, GemmArgs ga) {
  const int ct = blockIdx.x, rt = blockIdx.y;
  const TileDesc d = ga.d[ct];
  const int m0 = rt * 128;
  __shared__ __align__(16) u16 lA[2][2][4][128][8];
  __shared__ __align__(16) u16 lB[2][2][4][128][8];
  const int tid = threadIdx.x;
  const int w = tid >> 6, lane = tid & 63;
  const int wm = w >> 1, wn = w & 1;

  f32x4 acc[4][4];
#pragma unroll
  for (int a = 0; a < 4; ++a)
#pragma unroll
    for (int b = 0; b < 4; ++b)
#pragma unroll
      for (int r = 0; r < 4; ++r) acc[a][b][r] = 0.f;

  auto stage = [&](int buf, int kg) {
    GLD16(Ap + ((size_t)kg * 1024 + m0 + lane) * 8, &lA[buf][0][w][0][0]);
    GLD16(Ap + ((size_t)kg * 1024 + m0 + 64 + lane) * 8, &lA[buf][0][w][64][0]);
    GLD16(Ap + aps + ((size_t)kg * 1024 + m0 + lane) * 8, &lA[buf][1][w][0][0]);
    GLD16(Ap + aps + ((size_t)kg * 1024 + m0 + 64 + lane) * 8, &lA[buf][1][w][64][0]);
    GLD16(d.Blo + ((size_t)kg * d.ldNlo + lane) * 8, &lB[buf][0][w][0][0]);
    GLD16(d.Bhi + ((size_t)kg * d.ldNhi + lane) * 8, &lB[buf][0][w][64][0]);
    GLD16(d.Blo + d.bps + ((size_t)kg * d.ldNlo + lane) * 8, &lB[buf][1][w][0][0]);
    GLD16(d.Bhi + d.bps + ((size_t)kg * d.ldNhi + lane) * 8, &lB[buf][1][w][64][0]);
  };

  stage(0, w);
  const int kq = lane >> 4, fr = lane & 15;
  for (int ks = 0; ks < NK; ++ks) {
    __syncthreads();
    if (ks + 1 < NK) stage((ks + 1) & 1, (ks + 1) * 4 + w);
    const int cb = ks & 1;
    bf16x8 aFh[4], aFl[4], bFh[4], bFl[4];
#pragma unroll
    for (int f = 0; f < 4; ++f) {
      aFh[f] = *reinterpret_cast<const bf16x8*>(&lA[cb][0][kq][wm * 64 + f * 16 + fr][0]);
      aFl[f] = *reinterpret_cast<const bf16x8*>(&lA[cb][1][kq][wm * 64 + f * 16 + fr][0]);
      bFh[f] = *reinterpret_cast<const bf16x8*>(&lB[cb][0][kq][wn * 64 + f * 16 + fr][0]);
      bFl[f] = *reinterpret_cast<const bf16x8*>(&lB[cb][1][kq][wn * 64 + f * 16 + fr][0]);
    }
#pragma unroll
    for (int fm = 0; fm < 4; ++fm)
#pragma unroll
      for (int fn = 0; fn < 4; ++fn) {
        acc[fm][fn] = __builtin_amdgcn_mfma_f32_16x16x32_bf16(aFh[fm], bFh[fn],
                                                              acc[fm][fn], 0, 0, 0);
        acc[fm][fn] = __builtin_amdgcn_mfma_f32_16x16x32_bf16(aFl[fm], bFh[fn],
                                                              acc[fm][fn], 0, 0, 0);
        acc[fm][fn] = __builtin_amdgcn_mfma_f32_16x16x32_bf16(aFh[fm], bFl[fn],
                                                              acc[fm][fn], 0, 0, 0);
      }
  }
  float* Cb = (wn == 0) ? d.Clo : d.Chi;
  const int ldc = (wn == 0) ? d.ldClo : d.ldChi;
  if (d.mode != 1) {
#pragma unroll
    for (int fm = 0; fm < 4; ++fm)
#pragma unroll
      for (int fn = 0; fn < 4; ++fn)
#pragma unroll
        for (int r = 0; r < 4; ++r) {
          int row = m0 + wm * 64 + fm * 16 + (lane >> 4) * 4 + r;
          int cl = fn * 16 + fr;
          Cb[(size_t)row * ldc + cl] = acc[fm][fn][r];
        }
  }
  if (d.mode >= 1) {
#pragma unroll
    for (int fm = 0; fm < 4; ++fm)
#pragma unroll
      for (int fn = 0; fn < 4; ++fn)
#pragma unroll
        for (int r = 0; r < 4; ++r) {
          int row = m0 + wm * 64 + fm * 16 + (lane >> 4) * 4 + r;
          int gc = d.n0 + wn * 64 + fn * 16 + fr;
          float v = acc[fm][fn][r];
          u16 hb = f2bf(v);
          u16 lb = f2bf(v - bf2f(hb));
          size_t idx = ((size_t)(gc >> 3) * 1024 + row) * 8 + (gc & 7);
          d.Cp[idx] = hb;
          d.Cp[idx + d.cpps] = lb;
        }
  }
}

// ---------------- fp32 index-path GEMMs, 4 tokens per block ----------------
__global__ __launch_bounds__(256) void idx_kernel(
    const float* __restrict__ h, const float* __restrict__ q_lat,
    const float* __restrict__ Wikv, const float* __restrict__ Wiz,
    const float* __restrict__ Wiuq, float* __restrict__ hikv,
    float* __restrict__ hiz, float* __restrict__ qib) {
  const int t0 = blockIdx.x * 4;
  const int tid = threadIdx.x;
  __shared__ float hs[4][Dn];
  __shared__ float ql[4][DQn];
  for (int i = tid; i < 4 * Dn; i += 256)
    hs[i >> 9][i & 511] = h[(size_t)(t0 + (i >> 9)) * Dn + (i & 511)];
  for (int i = tid; i < 4 * DQn; i += 256)
    ql[i >> 8][i & 255] = q_lat[(size_t)(t0 + (i >> 8)) * DQn + (i & 255)];
  __syncthreads();
  if (tid < 128) {
    const float* Wm = (tid < 64) ? Wikv : Wiz;
    const int ci = tid & 63;
    float a0 = 0.f, a1 = 0.f, a2 = 0.f, a3 = 0.f;
#pragma unroll 8
    for (int k = 0; k < Dn; ++k) {
      float wv = Wm[k * CIn + ci];
      a0 += hs[0][k] * wv;
      a1 += hs[1][k] * wv;
      a2 += hs[2][k] * wv;
      a3 += hs[3][k] * wv;
    }
    float* dst = (tid < 64) ? hikv : hiz;
    dst[(size_t)(t0 + 0) * CIn + ci] = a0;
    dst[(size_t)(t0 + 1) * CIn + ci] = a1;
    dst[(size_t)(t0 + 2) * CIn + ci] = a2;
    dst[(size_t)(t0 + 3) * CIn + ci] = a3;
  } else {
    const int jj = tid - 128;
    float a0 = 0.f, a1 = 0.f, a2 = 0.f, a3 = 0.f;
#pragma unroll 8
    for (int k = 0; k < DQn; ++k) {
      float wv = Wiuq[k * 128 + jj];
      a0 += ql[0][k] * wv;
      a1 += ql[1][k] * wv;
      a2 += ql[2][k] * wv;
      a3 += ql[3][k] * wv;
    }
    qib[(size_t)(t0 + 0) * 128 + jj] = a0;
    qib[(size_t)(t0 + 1) * 128 + jj] = a1;
    qib[(size_t)(t0 + 2) * 128 + jj] = a2;
    qib[(size_t)(t0 + 3) * 128 + jj] = a3;
  }
}

// ---------------- merged phrase aggregation + RMS/RoPE ----------------
// blocks 0..127: phrase p; blocks 128..1151: rmsrope t = blockIdx-128.
__global__ __launch_bounds__(512) void phrase_rope_kernel(
    const int* __restrict__ maskbuf, const int* __restrict__ tokbuf,
    const int* __restrict__ endbuf, const float* __restrict__ hckv,
    const float* __restrict__ hcz, const float* __restrict__ hikv,
    const float* __restrict__ hiz, const float* __restrict__ Bcsa,
    const float* __restrict__ Bidx, const float* __restrict__ knw,
    const float* __restrict__ qnw, float* __restrict__ ccsa,
    float* __restrict__ kcsa, float* __restrict__ kidx,
    float* __restrict__ q, const float* __restrict__ kv,
    float* __restrict__ ksw) {
  const int tid = threadIdx.x;
  const int c = tid & 63;
  const float sgn = (c < 32) ? -1.f : 1.f;

  if (blockIdx.x >= Pn) {
    // ---- rmsrope for token t ----
    const int t = blockIdx.x - Pn;
    const float fr = (float)t * powf(10000.0f, -(float)(c & 31) / 32.0f);
    const float cv = cosf(fr), sv = sinf(fr);
    {
      float x = q[t * Dn + tid];
      float ss = x * x;
#pragma unroll
      for (int off = 32; off; off >>= 1) ss += __shfl_xor(ss, off, 64);
      float xr = x * rsqrtf(ss / (float)Cn + 1e-6f) * qnw[c];
      float pr = __shfl_xor(xr, 32, 64);
      q[t * Dn + tid] = xr * cv + sgn * pr * sv;
    }
    {
      float y = kv[t * Dn + tid];
      float ss = y * y;
#pragma unroll
      for (int off = 32; off; off >>= 1) ss += __shfl_xor(ss, off, 64);
      float yr = y * rsqrtf(ss / (float)Cn + 1e-6f) * knw[c];
      float pr = __shfl_xor(yr, 32, 64);
      ksw[t * Dn + tid] = yr * cv + sgn * pr * sv;
    }
    return;
  }

  // ---- phrase p ----
  const int p = blockIdx.x;
  __shared__ int s_bytemode;
  __shared__ int s_tok[LM];
  __shared__ int s_m[LM];
  __shared__ int s_pos, s_anyv;

  if (tid == 0) s_bytemode = 0;
  __syncthreads();
  {
    unsigned wv = ((const unsigned*)maskbuf)[tid];
    if (wv > 1u) atomicOr(&s_bytemode, 1);
  }
  __syncthreads();
  const int bytemode = s_bytemode;
  if (tid < LM) {
    int mv;
    if (bytemode)
      mv = ((const unsigned char*)maskbuf)[p * LM + tid] != 0;
    else
      mv = maskbuf[p * LM + tid] != 0;
    s_m[tid] = mv;
    s_tok[tid] = tokbuf[p * LM + tid];
  }
  if (tid == 0) {
    int e = endbuf[p];
    s_pos = min(max(e, 0), Tn - 1);
  }
  __syncthreads();
  if (tid == 0) {
    int any = 0;
    for (int l = 0; l < LM; ++l) any |= s_m[l];
    s_anyv = any;
  }
  __syncthreads();
  const int anyv = s_anyv;
  const int pos = s_pos;
  const float fr = (float)pos * powf(10000.0f, -(float)(c & 31) / 32.0f);
  const float cv = cosf(fr), sv = sinf(fr);

  {
    float z[LM];
    float zmax = NEGV;
#pragma unroll
    for (int l = 0; l < LM; ++l) {
      float zv = hcz[s_tok[l] * Dn + tid] + Bcsa[l * (Hn * Cn) + tid];
      zv = s_m[l] ? zv : NEGV;
      z[l] = zv;
      zmax = fmaxf(zmax, zv);
    }
    float den = 0.f, num = 0.f;
#pragma unroll
    for (int l = 0; l < LM; ++l) {
      float e = expf(z[l] - zmax);
      den += e;
      num += e * hckv[s_tok[l] * Dn + tid];
    }
    float cc = anyv ? (num / den) : 0.f;
    ccsa[p * (Hn * Cn) + tid] = cc;

    float ss = cc * cc;
#pragma unroll
    for (int off = 32; off; off >>= 1) ss += __shfl_xor(ss, off, 64);
    float kn = cc * rsqrtf(ss / (float)Cn + 1e-6f) * knw[c];
    float pr = __shfl_xor(kn, 32, 64);
    kcsa[p * (Hn * Cn) + tid] = kn * cv + sgn * pr * sv;
  }

  if (tid < CIn) {
    float zk[LM];
    float zm = NEGV;
#pragma unroll
    for (int l = 0; l < LM; ++l) {
      float zv = hiz[s_tok[l] * CIn + tid] + Bidx[l * CIn + tid];
      zv = s_m[l] ? zv : NEGV;
      zk[l] = zv;
      zm = fmaxf(zm, zv);
    }
    float dk = 0.f, nk = 0.f;
#pragma unroll
    for (int l = 0; l < LM; ++l) {
      float e = expf(zk[l] - zm);
      dk += e;
      nk += e * hikv[s_tok[l] * CIn + tid];
    }
    float ki = anyv ? (nk / dk) : 0.f;
    float pr = __shfl_xor(ki, 32, 64);
    kidx[p * CIn + tid] = ki * cv + sgn * pr * sv;
  }
}

// ---------------- phrase scores + top-32 (fp32, LDS-transposed kidx) --------
__global__ __launch_bounds__(128) void score_topk_kernel(
    const float* __restrict__ hbuf, const float* __restrict__ Ww,
    const float* __restrict__ qi, const float* __restrict__ kidx,
    const int* __restrict__ endbuf, int* __restrict__ sel,
    int* __restrict__ selok) {
  const int t = blockIdx.x;
  const int tid = threadIdx.x;
  __shared__ float sqi[NIn * CIn];
  __shared__ float kT[CIn][Pn + 1];
  __shared__ float sI[Pn];
  __shared__ float sp0[128], sp1[128];

  sqi[tid] = qi[(size_t)t * (NIn * CIn) + tid];
  // coalesced float4 loads of kidx, transposed store into kT
#pragma unroll
  for (int it = 0; it < 16; ++it) {
    int idx4 = it * 128 + tid;  // 2048 float4 total
    float4 v = reinterpret_cast<const float4*>(kidx)[idx4];
    int p = idx4 >> 4;
    int c4 = (idx4 & 15) * 4;
    kT[c4 + 0][p] = v.x;
    kT[c4 + 1][p] = v.y;
    kT[c4 + 2][p] = v.z;
    kT[c4 + 3][p] = v.w;
  }
  float p0 = 0.f, p1 = 0.f;
#pragma unroll
  for (int e4 = 0; e4 < 4; ++e4) {
    int e = tid * 4 + e4;
    float hv = hbuf[(size_t)t * Dn + e];
    p0 += hv * Ww[e * NIn + 0];
    p1 += hv * Ww[e * NIn + 1];
  }
  sp0[tid] = p0;
  sp1[tid] = p1;
  __syncthreads();
  for (int srd = 64; srd; srd >>= 1) {
    if (tid < srd) {
      sp0[tid] += sp0[tid + srd];
      sp1[tid] += sp1[tid + srd];
    }
    __syncthreads();
  }
  const float ww0 = sp0[0], ww1 = sp1[0];

  {
    const int p = tid;
    float s0 = 0.f, s1 = 0.f;
#pragma unroll 16
    for (int ci = 0; ci < CIn; ++ci) {
      float kc = kT[ci][p];
      s0 += sqi[ci] * kc;
      s1 += sqi[CIn + ci] * kc;
    }
    float Iv = fmaxf(s0, 0.f) * ww0 + fmaxf(s1, 0.f) * ww1;
    int e = endbuf[p];
    if (!(e <= t && e >= 0)) Iv = NEGV;
    sI[p] = Iv;
  }
  __syncthreads();

  if (tid < 64) {
    float v0 = sI[tid], v1 = sI[tid + 64];
    for (int it = 0; it < TK; ++it) {
      float bv;
      int bi;
      if (v0 >= v1) { bv = v0; bi = tid; } else { bv = v1; bi = tid + 64; }
#pragma unroll
      for (int off = 32; off; off >>= 1) {
        float ov = __shfl_xor(bv, off, 64);
        int oi = __shfl_xor(bi, off, 64);
        if (ov > bv || (ov == bv && oi < bi)) { bv = ov; bi = oi; }
      }
      if (tid == 0) {
        sel[t * TK + it] = bi;
        selok[t * TK + it] = (bv > NEGV * 0.5f) ? 1 : 0;
      }
      if (bi == tid) v0 = -3.4e38f;
      if (bi == tid + 64) v1 = -3.4e38f;
    }
  }
}

// ---------------- attention v3 (split-bf16 packed output) ----------------
__global__ __launch_bounds__(256) void attn3_kernel(
    const float* __restrict__ q, const float* __restrict__ ksw,
    const float* __restrict__ kv, const float* __restrict__ kcsa,
    const float* __restrict__ ccsa, const int* __restrict__ sel,
    const int* __restrict__ selok, const float* __restrict__ sink,
    u16* __restrict__ atp) {
  const int tid = threadIdx.x;
  const int wid = tid >> 6, lane = tid & 63;
  const int g = lane >> 4;
  const int gl = lane & 15;
  const int pair = blockIdx.x * 4 + wid;
  const int t = pair >> 3, h = pair & 7;

  __shared__ float slog[4][164];
  __shared__ int s_sel[4][TK];
  __shared__ int s_ok[4][TK];

  if (lane < TK) {
    s_sel[wid][lane] = sel[t * TK + lane];
    s_ok[wid][lane] = selok[t * TK + lane];
  }
  const int hc = h * Cn + gl * 4;
  const float4 qf = *reinterpret_cast<const float4*>(&q[t * Dn + hc]);
  float* myslog = slog[wid];

#pragma unroll 4
  for (int pass = 0; pass < 32; ++pass) {
    int w = pass * 4 + g;
    int src = t + w - (NW - 1);
    int srcc = max(src, 0);
    float4 kk = *reinterpret_cast<const float4*>(&ksw[srcc * Dn + hc]);
    float acc = qf.x * kk.x + qf.y * kk.y + qf.z * kk.z + qf.w * kk.w;
#pragma unroll
    for (int off = 1; off < 16; off <<= 1) acc += __shfl_xor(acc, off, 64);
    if (gl == 0) myslog[TK + w] = (src >= 0) ? acc * 0.125f : NEGV;
  }
#pragma unroll 2
  for (int pass = 0; pass < 8; ++pass) {
    int s = pass * 4 + g;
    int se = s_sel[wid][s];
    float4 kk = *reinterpret_cast<const float4*>(&kcsa[se * Dn + hc]);
    float acc = qf.x * kk.x + qf.y * kk.y + qf.z * kk.z + qf.w * kk.w;
#pragma unroll
    for (int off = 1; off < 16; off <<= 1) acc += __shfl_xor(acc, off, 64);
    if (gl == 0) myslog[s] = s_ok[wid][s] ? acc * 0.125f : NEGV;
  }
  if (lane == 0) myslog[160] = sink[h];

  float x0 = myslog[lane];
  float x1 = myslog[lane + 64];
  float x2 = (lane < 33) ? myslog[lane + 128] : NEGV;
  float m = fmaxf(x0, fmaxf(x1, x2));
#pragma unroll
  for (int off = 32; off; off >>= 1) m = fmaxf(m, __shfl_xor(m, off, 64));
  float e0 = expf(x0 - m), e1 = expf(x1 - m);
  float e2 = (lane < 33) ? expf(x2 - m) : 0.f;
  float sden = e0 + e1 + e2;
#pragma unroll
  for (int off = 32; off; off >>= 1) sden += __shfl_xor(sden, off, 64);
  const float inv = 1.f / sden;
  myslog[lane] = e0 * inv;
  myslog[lane + 64] = e1 * inv;
  if (lane < 33) myslog[lane + 128] = e2 * inv;

  float4 acc = make_float4(0.f, 0.f, 0.f, 0.f);
#pragma unroll 4
  for (int pass = 0; pass < 32; ++pass) {
    int w = pass * 4 + g;
    int src = t + w - (NW - 1);
    int srcc = max(src, 0);
    float pv = myslog[TK + w];
    pv = (src >= 0) ? pv : 0.f;
    float4 vv = *reinterpret_cast<const float4*>(&kv[srcc * Dn + hc]);
    acc.x += pv * vv.x;
    acc.y += pv * vv.y;
    acc.z += pv * vv.z;
    acc.w += pv * vv.w;
  }
#pragma unroll 2
  for (int pass = 0; pass < 8; ++pass) {
    int s = pass * 4 + g;
    float pv = myslog[s];
    int se = s_sel[wid][s];
    float4 vv = *reinterpret_cast<const float4*>(&ccsa[se * Dn + hc]);
    acc.x += pv * vv.x;
    acc.y += pv * vv.y;
    acc.z += pv * vv.z;
    acc.w += pv * vv.w;
  }
  acc.x += __shfl_xor(acc.x, 16, 64);
  acc.y += __shfl_xor(acc.y, 16, 64);
  acc.z += __shfl_xor(acc.z, 16, 64);
  acc.w += __shfl_xor(acc.w, 16, 64);
  acc.x += __shfl_xor(acc.x, 32, 64);
  acc.y += __shfl_xor(acc.y, 32, 64);
  acc.z += __shfl_xor(acc.z, 32, 64);
  acc.w += __shfl_xor(acc.w, 32, 64);
  if (lane < 16) {
    float vals[4] = {acc.x, acc.y, acc.z, acc.w};
    int colb = h * Cn + lane * 4;
#pragma unroll
    for (int r = 0; r < 4; ++r) {
      int gc = colb + r;
      float v = vals[r];
      u16 hb = f2bf(v);
      u16 lb = f2bf(v - bf2f(hb));
      size_t idx = ((size_t)(gc >> 3) * 1024 + t) * 8 + (gc & 7);
      atp[idx] = hb;
      atp[idx + 524288] = lb;
    }
  }
}

// ---------------- host launcher ----------------
extern "C" void kernel_launch(void* const* d_in, const int* in_sizes, int n_in,
                              void* d_out, int out_size, void* d_ws,
                              size_t ws_size, hipStream_t stream) {
  const float* h = (const float*)d_in[0];
  const int* mask = (const int*)d_in[1];
  const int* tok = (const int*)d_in[2];
  const int* endp = (const int*)d_in[3];
  const float* W_dq = (const float*)d_in[5];
  const float* W_uq = (const float*)d_in[6];
  const float* W_csa_kv = (const float*)d_in[7];
  const float* W_csa_z = (const float*)d_in[8];
  const float* B_csa = (const float*)d_in[9];
  const float* W_idx_kv = (const float*)d_in[10];
  const float* W_idx_z = (const float*)d_in[11];
  const float* B_idx = (const float*)d_in[12];
  const float* W_iuq = (const float*)d_in[13];
  const float* W_w = (const float*)d_in[14];
  const float* W_swkv = (const float*)d_in[15];
  const float* qnw = (const float*)d_in[16];
  const float* knw = (const float*)d_in[17];
  const float* W_o = (const float*)d_in[18];
  const float* sink = (const float*)d_in[19];

  float* ws = (float*)d_ws;
  u16* hA = (u16*)(ws + 0);          // 2 planes x 524288 u16; dead after K1
  float* qbuf = ws + 0;              // alias (written by K2)
  u16* qlP = (u16*)(ws + 524288);    // 2 planes x 262144 u16; A of K2
  float* hckv = ws + 786432;         // dead after phrase_rope
  u16* atP = (u16*)(ws + 786432);    // alias (written by attn)
  float* hcz = ws + 1310720;
  float* kvb = ws + 1835008;
  float* hikv = ws + 2359296;
  float* hiz = ws + 2424832;
  float* q_lat = ws + 2490368;
  float* ccsa = ws + 2752512;
  float* kcsa = ws + 2818048;
  float* kidx = ws + 2883584;
  int* seli = (int*)(ws + 2891776);
  int* selok = (int*)(ws + 2924544);
  float* qib = ws + 2957312;
  float* kswb = ws + 3088384;        // own buffer (no alias: merged launch)
  u16* pW = (u16*)(ws + 3612672);    // split-packed weights
  u16* pWdq = pW;
  u16* pWckv = pW + 262144;
  u16* pWcz = pW + 786432;
  u16* pWsw = pW + 1310720;
  u16* pWuq = pW + 1835008;
  u16* pWo = pW + 2097152;
  float* outp = (float*)d_out;

  // ---- pack all GEMM operands to split bf16 ----
  {
    PackJobs pj{};
    const float* srcs[7] = {h, W_dq, W_csa_kv, W_csa_z, W_swkv, W_uq, W_o};
    u16* dsts[7] = {hA, pWdq, pWckv, pWcz, pWsw, pWuq, pWo};
    int Ns[7] = {0, 256, 512, 512, 512, 512, 512};
    int logNs[7] = {0, 8, 9, 9, 9, 9, 9};
    int Ks[7] = {512, 512, 512, 512, 512, 256, 512};
    int isA[7] = {1, 0, 0, 0, 0, 0, 0};
    int pss[7] = {524288, 131072, 262144, 262144, 262144, 131072, 262144};
    int s = 0;
    for (int i = 0; i < 7; ++i) {
      pj.src[i] = srcs[i];
      pj.dst[i] = dsts[i];
      pj.N[i] = Ns[i];
      pj.logN[i] = logNs[i];
      pj.isA[i] = isA[i];
      pj.ps[i] = pss[i];
      pj.start[i] = s;
      s += isA[i] ? 1024 * (Ks[i] / 8) : (Ks[i] / 8) * Ns[i];
    }
    pj.start[7] = s;
    pack_all<<<(s + 255) / 256, 256, 0, stream>>>(pj);
  }

  auto normTile = [](const u16* pB, int N, int n0, float* C, int ldc, int bps) {
    TileDesc td{};
    td.Blo = pB + n0 * 8;
    td.Bhi = pB + (n0 + 64) * 8;
    td.ldNlo = td.ldNhi = N;
    td.Clo = C + n0;
    td.Chi = C + n0 + 64;
    td.ldClo = td.ldChi = ldc;
    td.mode = 0;
    td.bps = bps;
    return td;
  };

  // ---- K1: h @ {W_dq(mode2), W_csa_kv, W_csa_z, W_swkv} ----
  {
    GemmArgs ga{};
    int nt = 0;
    for (int n0 = 0; n0 < 256; n0 += 128) {
      TileDesc td = normTile(pWdq, 256, n0, q_lat, 256, 131072);
      td.mode = 2;
      td.Cp = qlP;
      td.cpps = 262144;
      td.n0 = n0;
      ga.d[nt++] = td;
    }
    for (int n0 = 0; n0 < 512; n0 += 128) ga.d[nt++] = normTile(pWckv, 512, n0, hckv, 512, 262144);
    for (int n0 = 0; n0 < 512; n0 += 128) ga.d[nt++] = normTile(pWcz, 512, n0, hcz, 512, 262144);
    for (int n0 = 0; n0 < 512; n0 += 128) ga.d[nt++] = normTile(pWsw, 512, n0, kvb, 512, 262144);
    gemm_bf16<<<dim3(nt, 8), 256, 0, stream>>>(hA, 16, 524288, ga);
  }
  // ---- K2: q_lat @ W_uq (split bf16) -> qbuf ----
  {
    GemmArgs ga{};
    int nt = 0;
    for (int n0 = 0; n0 < 512; n0 += 128) ga.d[nt++] = normTile(pWuq, 512, n0, qbuf, 512, 131072);
    gemm_bf16<<<dim3(nt, 8), 256, 0, stream>>>(qlP, 8, 262144, ga);
  }
  // ---- fp32 idx-path GEMMs (4 tokens/block) ----
  idx_kernel<<<Tn / 4, 256, 0, stream>>>(h, q_lat, W_idx_kv, W_idx_z, W_iuq,
                                         hikv, hiz, qib);
  // ---- merged phrase aggregation + q/k_sw rms+rope ----
  phrase_rope_kernel<<<Pn + Tn, 512, 0, stream>>>(
      mask, tok, endp, hckv, hcz, hikv, hiz, B_csa, B_idx, knw, qnw, ccsa,
      kcsa, kidx, qbuf, kvb, kswb);
  // ---- scores + top-32 ----
  score_topk_kernel<<<Tn, 128, 0, stream>>>(h, W_w, qib, kidx, endp, seli,
                                            selok);
  // ---- attention (writes split-packed atP, aliases hckv) ----
  attn3_kernel<<<dim3(Tn * Hn / 4), 256, 0, stream>>>(qbuf, kswb, kvb, kcsa,
                                                      ccsa, seli, selok, sink,
                                                      atP);
  // ---- K7: attno @ W_o (split bf16) -> out ----
  {
    GemmArgs ga{};
    int nt = 0;
    for (int n0 = 0; n0 < 512; n0 += 128) ga.d[nt++] = normTile(pWo, 512, n0, outp, 512, 262144);
    gemm_bf16<<<dim3(nt, 8), 256, 0, stream>>>(atP, 16, 524288, ga);
  }
  (void)in_sizes; (void)n_in; (void)out_size; (void)ws_size;
}

// Round 8
// 136.558 us; speedup vs baseline: 1.3529x; 1.1061x over previous
//
#include <hip/hip_runtime.h>
#include <cmath>

// ---------------- constants (match reference) ----------------
static constexpr int Tn = 1024, Dn = 512, Hn = 8, Cn = 64, DQn = 256,
                     NIn = 2, CIn = 64, TK = 32, LM = 16, NW = 128, Pn = 128;
#define NEGV (-1e30f)

typedef unsigned short u16;
typedef __bf16 bf16x8 __attribute__((ext_vector_type(8)));
typedef float f32x4 __attribute__((ext_vector_type(4)));

__device__ __forceinline__ u16 f2bf(float x) {
  unsigned u = __float_as_uint(x);
  return (u16)((u + 0x7fffu + ((u >> 16) & 1u)) >> 16);
}
__device__ __forceinline__ float bf2f(u16 b) {
  return __uint_as_float((unsigned)b << 16);
}

// ---------------- pack: fp32 -> split bf16 (hi+lo), k-grouped-by-8 ----------
struct PackJobs {
  const float* src[7];
  u16* dst[7];
  int start[8];
  int N[7];
  int logN[7];
  int isA[7];
  int ps[7];  // plane size in u16 elements
};

__global__ __launch_bounds__(256) void pack_all(PackJobs pj) {
  int i = blockIdx.x * 256 + threadIdx.x;
  if (i >= pj.start[7]) return;
  int j = 0;
  while (i >= pj.start[j + 1]) ++j;
  int local = i - pj.start[j];
  const float* s = pj.src[j];
  u16* dh = pj.dst[j];
  u16* dl = dh + pj.ps[j];
  float x[8];
  size_t idx;
  if (pj.isA[j]) {
    int m = local & 1023;
    int kg = local >> 10;
    const float4* p = reinterpret_cast<const float4*>(s + (size_t)m * 512 + kg * 8);
    float4 a = p[0], b = p[1];
    x[0] = a.x; x[1] = a.y; x[2] = a.z; x[3] = a.w;
    x[4] = b.x; x[5] = b.y; x[6] = b.z; x[7] = b.w;
    idx = ((size_t)kg * 1024 + m) * 8;
  } else {
    int N = pj.N[j];
    int n = local & (N - 1);
    int kg = local >> pj.logN[j];
#pragma unroll
    for (int e = 0; e < 8; ++e) x[e] = s[(size_t)(kg * 8 + e) * N + n];
    idx = ((size_t)kg * N + n) * 8;
  }
  union { u16 u[8]; int4 v; } oh, ol;
#pragma unroll
  for (int e = 0; e < 8; ++e) {
    u16 hb = f2bf(x[e]);
    oh.u[e] = hb;
    ol.u[e] = f2bf(x[e] - bf2f(hb));
  }
  *reinterpret_cast<int4*>(dh + idx) = oh.v;
  *reinterpret_cast<int4*>(dl + idx) = ol.v;
}

// ---------------- split-bf16 MFMA GEMM (templated M-tile) ----------------
// Tile MT x 128 where MT = FMW*32; 4 waves arranged 2(M) x 2(N), each wave
// FMW x 4 frags of 16x16x32. BK=32, double-buffered LDS, hi/lo planes,
// 3 MFMA per fragment pair (AhBh + AlBh + AhBl).
struct TileDesc {
  const u16* Blo;
  const u16* Bhi;
  float* Clo;
  float* Chi;
  u16* Cp;
  int ldNlo, ldNhi, ldClo, ldChi, mode, n0, bps, cpps;
};
struct GemmArgs {
  TileDesc d[15];
};

#define GLD16(gp, lp)                                                     \
  __builtin_amdgcn_global_load_lds(                                      \
      (const __attribute__((address_space(1))) unsigned int*)(gp),       \
      (__attribute__((address_space(3))) unsigned int*)(lp), 16, 0, 0)

template <int FMW>
__global__ __launch_bounds__(256) void gemm_bf16(const u16* __restrict__ Ap,
                                                 int NK, int aps, GemmArgs ga) {
  constexpr int MT = FMW * 32;
  const int ct = blockIdx.x, rt = blockIdx.y;
  const TileDesc d = ga.d[ct];
  const int m0 = rt * MT;
  __shared__ __align__(16) u16 lA[2][2][4][MT][8];
  __shared__ __align__(16) u16 lB[2][2][4][128][8];
  const int tid = threadIdx.x;
  const int w = tid >> 6, lane = tid & 63;
  const int wm = w >> 1, wn = w & 1;

  f32x4 acc[FMW][4];
#pragma unroll
  for (int a = 0; a < FMW; ++a)
#pragma unroll
    for (int b = 0; b < 4; ++b)
#pragma unroll
      for (int r = 0; r < 4; ++r) acc[a][b][r] = 0.f;

  auto stage = [&](int buf, int kg) {
#pragma unroll
    for (int r0 = 0; r0 < MT; r0 += 64) {
      GLD16(Ap + ((size_t)kg * 1024 + m0 + r0 + lane) * 8, &lA[buf][0][w][r0][0]);
      GLD16(Ap + aps + ((size_t)kg * 1024 + m0 + r0 + lane) * 8, &lA[buf][1][w][r0][0]);
    }
    GLD16(d.Blo + ((size_t)kg * d.ldNlo + lane) * 8, &lB[buf][0][w][0][0]);
    GLD16(d.Bhi + ((size_t)kg * d.ldNhi + lane) * 8, &lB[buf][0][w][64][0]);
    GLD16(d.Blo + d.bps + ((size_t)kg * d.ldNlo + lane) * 8, &lB[buf][1][w][0][0]);
    GLD16(d.Bhi + d.bps + ((size_t)kg * d.ldNhi + lane) * 8, &lB[buf][1][w][64][0]);
  };

  stage(0, w);
  const int kq = lane >> 4, fr = lane & 15;
  for (int ks = 0; ks < NK; ++ks) {
    __syncthreads();
    if (ks + 1 < NK) stage((ks + 1) & 1, (ks + 1) * 4 + w);
    const int cb = ks & 1;
    bf16x8 aFh[FMW], aFl[FMW], bFh[4], bFl[4];
#pragma unroll
    for (int f = 0; f < FMW; ++f) {
      aFh[f] = *reinterpret_cast<const bf16x8*>(&lA[cb][0][kq][wm * (FMW * 16) + f * 16 + fr][0]);
      aFl[f] = *reinterpret_cast<const bf16x8*>(&lA[cb][1][kq][wm * (FMW * 16) + f * 16 + fr][0]);
    }
#pragma unroll
    for (int f = 0; f < 4; ++f) {
      bFh[f] = *reinterpret_cast<const bf16x8*>(&lB[cb][0][kq][wn * 64 + f * 16 + fr][0]);
      bFl[f] = *reinterpret_cast<const bf16x8*>(&lB[cb][1][kq][wn * 64 + f * 16 + fr][0]);
    }
#pragma unroll
    for (int fm = 0; fm < FMW; ++fm)
#pragma unroll
      for (int fn = 0; fn < 4; ++fn) {
        acc[fm][fn] = __builtin_amdgcn_mfma_f32_16x16x32_bf16(aFh[fm], bFh[fn],
                                                              acc[fm][fn], 0, 0, 0);
        acc[fm][fn] = __builtin_amdgcn_mfma_f32_16x16x32_bf16(aFl[fm], bFh[fn],
                                                              acc[fm][fn], 0, 0, 0);
        acc[fm][fn] = __builtin_amdgcn_mfma_f32_16x16x32_bf16(aFh[fm], bFl[fn],
                                                              acc[fm][fn], 0, 0, 0);
      }
  }
  float* Cb = (wn == 0) ? d.Clo : d.Chi;
  const int ldc = (wn == 0) ? d.ldClo : d.ldChi;
  if (d.mode != 1) {
#pragma unroll
    for (int fm = 0; fm < FMW; ++fm)
#pragma unroll
      for (int fn = 0; fn < 4; ++fn)
#pragma unroll
        for (int r = 0; r < 4; ++r) {
          int row = m0 + wm * (FMW * 16) + fm * 16 + (lane >> 4) * 4 + r;
          int cl = fn * 16 + fr;
          Cb[(size_t)row * ldc + cl] = acc[fm][fn][r];
        }
  }
  if (d.mode >= 1) {
#pragma unroll
    for (int fm = 0; fm < FMW; ++fm)
#pragma unroll
      for (int fn = 0; fn < 4; ++fn)
#pragma unroll
        for (int r = 0; r < 4; ++r) {
          int row = m0 + wm * (FMW * 16) + fm * 16 + (lane >> 4) * 4 + r;
          int gc = d.n0 + wn * 64 + fn * 16 + fr;
          float v = acc[fm][fn][r];
          u16 hb = f2bf(v);
          u16 lb = f2bf(v - bf2f(hb));
          size_t idx = ((size_t)(gc >> 3) * 1024 + row) * 8 + (gc & 7);
          d.Cp[idx] = hb;
          d.Cp[idx + d.cpps] = lb;
        }
  }
}

// ---------------- fp32 index-path GEMMs, 4 tokens per block ----------------
__global__ __launch_bounds__(256) void idx_kernel(
    const float* __restrict__ h, const float* __restrict__ q_lat,
    const float* __restrict__ Wikv, const float* __restrict__ Wiz,
    const float* __restrict__ Wiuq, float* __restrict__ hikv,
    float* __restrict__ hiz, float* __restrict__ qib) {
  const int t0 = blockIdx.x * 4;
  const int tid = threadIdx.x;
  __shared__ float hs[4][Dn];
  __shared__ float ql[4][DQn];
  for (int i = tid; i < 4 * Dn; i += 256)
    hs[i >> 9][i & 511] = h[(size_t)(t0 + (i >> 9)) * Dn + (i & 511)];
  for (int i = tid; i < 4 * DQn; i += 256)
    ql[i >> 8][i & 255] = q_lat[(size_t)(t0 + (i >> 8)) * DQn + (i & 255)];
  __syncthreads();
  if (tid < 128) {
    const float* Wm = (tid < 64) ? Wikv : Wiz;
    const int ci = tid & 63;
    float a0 = 0.f, a1 = 0.f, a2 = 0.f, a3 = 0.f;
#pragma unroll 8
    for (int k = 0; k < Dn; ++k) {
      float wv = Wm[k * CIn + ci];
      a0 += hs[0][k] * wv;
      a1 += hs[1][k] * wv;
      a2 += hs[2][k] * wv;
      a3 += hs[3][k] * wv;
    }
    float* dst = (tid < 64) ? hikv : hiz;
    dst[(size_t)(t0 + 0) * CIn + ci] = a0;
    dst[(size_t)(t0 + 1) * CIn + ci] = a1;
    dst[(size_t)(t0 + 2) * CIn + ci] = a2;
    dst[(size_t)(t0 + 3) * CIn + ci] = a3;
  } else {
    const int jj = tid - 128;
    float a0 = 0.f, a1 = 0.f, a2 = 0.f, a3 = 0.f;
#pragma unroll 8
    for (int k = 0; k < DQn; ++k) {
      float wv = Wiuq[k * 128 + jj];
      a0 += ql[0][k] * wv;
      a1 += ql[1][k] * wv;
      a2 += ql[2][k] * wv;
      a3 += ql[3][k] * wv;
    }
    qib[(size_t)(t0 + 0) * 128 + jj] = a0;
    qib[(size_t)(t0 + 1) * 128 + jj] = a1;
    qib[(size_t)(t0 + 2) * 128 + jj] = a2;
    qib[(size_t)(t0 + 3) * 128 + jj] = a3;
  }
}

// ---------------- merged phrase aggregation + RMS/RoPE ----------------
__global__ __launch_bounds__(512) void phrase_rope_kernel(
    const int* __restrict__ maskbuf, const int* __restrict__ tokbuf,
    const int* __restrict__ endbuf, const float* __restrict__ hckv,
    const float* __restrict__ hcz, const float* __restrict__ hikv,
    const float* __restrict__ hiz, const float* __restrict__ Bcsa,
    const float* __restrict__ Bidx, const float* __restrict__ knw,
    const float* __restrict__ qnw, float* __restrict__ ccsa,
    float* __restrict__ kcsa, float* __restrict__ kidx,
    float* __restrict__ q, const float* __restrict__ kv,
    float* __restrict__ ksw) {
  const int tid = threadIdx.x;
  const int c = tid & 63;
  const float sgn = (c < 32) ? -1.f : 1.f;

  if (blockIdx.x >= Pn) {
    const int t = blockIdx.x - Pn;
    const float fr = (float)t * powf(10000.0f, -(float)(c & 31) / 32.0f);
    const float cv = cosf(fr), sv = sinf(fr);
    {
      float x = q[t * Dn + tid];
      float ss = x * x;
#pragma unroll
      for (int off = 32; off; off >>= 1) ss += __shfl_xor(ss, off, 64);
      float xr = x * rsqrtf(ss / (float)Cn + 1e-6f) * qnw[c];
      float pr = __shfl_xor(xr, 32, 64);
      q[t * Dn + tid] = xr * cv + sgn * pr * sv;
    }
    {
      float y = kv[t * Dn + tid];
      float ss = y * y;
#pragma unroll
      for (int off = 32; off; off >>= 1) ss += __shfl_xor(ss, off, 64);
      float yr = y * rsqrtf(ss / (float)Cn + 1e-6f) * knw[c];
      float pr = __shfl_xor(yr, 32, 64);
      ksw[t * Dn + tid] = yr * cv + sgn * pr * sv;
    }
    return;
  }

  const int p = blockIdx.x;
  __shared__ int s_bytemode;
  __shared__ int s_tok[LM];
  __shared__ int s_m[LM];
  __shared__ int s_pos, s_anyv;

  if (tid == 0) s_bytemode = 0;
  __syncthreads();
  {
    unsigned wv = ((const unsigned*)maskbuf)[tid];
    if (wv > 1u) atomicOr(&s_bytemode, 1);
  }
  __syncthreads();
  const int bytemode = s_bytemode;
  if (tid < LM) {
    int mv;
    if (bytemode)
      mv = ((const unsigned char*)maskbuf)[p * LM + tid] != 0;
    else
      mv = maskbuf[p * LM + tid] != 0;
    s_m[tid] = mv;
    s_tok[tid] = tokbuf[p * LM + tid];
  }
  if (tid == 0) {
    int e = endbuf[p];
    s_pos = min(max(e, 0), Tn - 1);
  }
  __syncthreads();
  if (tid == 0) {
    int any = 0;
    for (int l = 0; l < LM; ++l) any |= s_m[l];
    s_anyv = any;
  }
  __syncthreads();
  const int anyv = s_anyv;
  const int pos = s_pos;
  const float fr = (float)pos * powf(10000.0f, -(float)(c & 31) / 32.0f);
  const float cv = cosf(fr), sv = sinf(fr);

  {
    float z[LM];
    float zmax = NEGV;
#pragma unroll
    for (int l = 0; l < LM; ++l) {
      float zv = hcz[s_tok[l] * Dn + tid] + Bcsa[l * (Hn * Cn) + tid];
      zv = s_m[l] ? zv : NEGV;
      z[l] = zv;
      zmax = fmaxf(zmax, zv);
    }
    float den = 0.f, num = 0.f;
#pragma unroll
    for (int l = 0; l < LM; ++l) {
      float e = expf(z[l] - zmax);
      den += e;
      num += e * hckv[s_tok[l] * Dn + tid];
    }
    float cc = anyv ? (num / den) : 0.f;
    ccsa[p * (Hn * Cn) + tid] = cc;

    float ss = cc * cc;
#pragma unroll
    for (int off = 32; off; off >>= 1) ss += __shfl_xor(ss, off, 64);
    float kn = cc * rsqrtf(ss / (float)Cn + 1e-6f) * knw[c];
    float pr = __shfl_xor(kn, 32, 64);
    kcsa[p * (Hn * Cn) + tid] = kn * cv + sgn * pr * sv;
  }

  if (tid < CIn) {
    float zk[LM];
    float zm = NEGV;
#pragma unroll
    for (int l = 0; l < LM; ++l) {
      float zv = hiz[s_tok[l] * CIn + tid] + Bidx[l * CIn + tid];
      zv = s_m[l] ? zv : NEGV;
      zk[l] = zv;
      zm = fmaxf(zm, zv);
    }
    float dk = 0.f, nk = 0.f;
#pragma unroll
    for (int l = 0; l < LM; ++l) {
      float e = expf(zk[l] - zm);
      dk += e;
      nk += e * hikv[s_tok[l] * CIn + tid];
    }
    float ki = anyv ? (nk / dk) : 0.f;
    float pr = __shfl_xor(ki, 32, 64);
    kidx[p * CIn + tid] = ki * cv + sgn * pr * sv;
  }
}

// ---------------- phrase scores + top-32 (fp32, LDS-transposed kidx) --------
__global__ __launch_bounds__(128) void score_topk_kernel(
    const float* __restrict__ hbuf, const float* __restrict__ Ww,
    const float* __restrict__ qi, const float* __restrict__ kidx,
    const int* __restrict__ endbuf, int* __restrict__ sel,
    int* __restrict__ selok) {
  const int t = blockIdx.x;
  const int tid = threadIdx.x;
  __shared__ float sqi[NIn * CIn];
  __shared__ float kT[CIn][Pn + 1];
  __shared__ float sI[Pn];
  __shared__ float sp0[128], sp1[128];

  sqi[tid] = qi[(size_t)t * (NIn * CIn) + tid];
#pragma unroll
  for (int it = 0; it < 16; ++it) {
    int idx4 = it * 128 + tid;
    float4 v = reinterpret_cast<const float4*>(kidx)[idx4];
    int p = idx4 >> 4;
    int c4 = (idx4 & 15) * 4;
    kT[c4 + 0][p] = v.x;
    kT[c4 + 1][p] = v.y;
    kT[c4 + 2][p] = v.z;
    kT[c4 + 3][p] = v.w;
  }
  float p0 = 0.f, p1 = 0.f;
#pragma unroll
  for (int e4 = 0; e4 < 4; ++e4) {
    int e = tid * 4 + e4;
    float hv = hbuf[(size_t)t * Dn + e];
    p0 += hv * Ww[e * NIn + 0];
    p1 += hv * Ww[e * NIn + 1];
  }
  sp0[tid] = p0;
  sp1[tid] = p1;
  __syncthreads();
  for (int srd = 64; srd; srd >>= 1) {
    if (tid < srd) {
      sp0[tid] += sp0[tid + srd];
      sp1[tid] += sp1[tid + srd];
    }
    __syncthreads();
  }
  const float ww0 = sp0[0], ww1 = sp1[0];

  {
    const int p = tid;
    float s0 = 0.f, s1 = 0.f;
#pragma unroll 16
    for (int ci = 0; ci < CIn; ++ci) {
      float kc = kT[ci][p];
      s0 += sqi[ci] * kc;
      s1 += sqi[CIn + ci] * kc;
    }
    float Iv = fmaxf(s0, 0.f) * ww0 + fmaxf(s1, 0.f) * ww1;
    int e = endbuf[p];
    if (!(e <= t && e >= 0)) Iv = NEGV;
    sI[p] = Iv;
  }
  __syncthreads();

  if (tid < 64) {
    float v0 = sI[tid], v1 = sI[tid + 64];
    for (int it = 0; it < TK; ++it) {
      float bv;
      int bi;
      if (v0 >= v1) { bv = v0; bi = tid; } else { bv = v1; bi = tid + 64; }
#pragma unroll
      for (int off = 32; off; off >>= 1) {
        float ov = __shfl_xor(bv, off, 64);
        int oi = __shfl_xor(bi, off, 64);
        if (ov > bv || (ov == bv && oi < bi)) { bv = ov; bi = oi; }
      }
      if (tid == 0) {
        sel[t * TK + it] = bi;
        selok[t * TK + it] = (bv > NEGV * 0.5f) ? 1 : 0;
      }
      if (bi == tid) v0 = -3.4e38f;
      if (bi == tid + 64) v1 = -3.4e38f;
    }
  }
}

// ---------------- attention v4: 4 consecutive t per block (L1 reuse) --------
// Block = 4 waves = 4 consecutive t for ONE head -> the ~131 shared window
// rows (34 KB head-slice) stay L1-resident across the 4 waves.
__global__ __launch_bounds__(256) void attn4_kernel(
    const float* __restrict__ q, const float* __restrict__ ksw,
    const float* __restrict__ kv, const float* __restrict__ kcsa,
    const float* __restrict__ ccsa, const int* __restrict__ sel,
    const int* __restrict__ selok, const float* __restrict__ sink,
    u16* __restrict__ atp) {
  const int tid = threadIdx.x;
  const int wid = tid >> 6, lane = tid & 63;
  const int g = lane >> 4;
  const int gl = lane & 15;
  const int h = blockIdx.x >> 8;
  const int t = ((blockIdx.x & 255) << 2) + wid;

  __shared__ float slog[4][164];
  __shared__ int s_sel[4][TK];
  __shared__ int s_ok[4][TK];

  if (lane < TK) {
    s_sel[wid][lane] = sel[t * TK + lane];
    s_ok[wid][lane] = selok[t * TK + lane];
  }
  const int hc = h * Cn + gl * 4;
  const float4 qf = *reinterpret_cast<const float4*>(&q[t * Dn + hc]);
  float* myslog = slog[wid];

#pragma unroll 4
  for (int pass = 0; pass < 32; ++pass) {
    int w = pass * 4 + g;
    int src = t + w - (NW - 1);
    int srcc = max(src, 0);
    float4 kk = *reinterpret_cast<const float4*>(&ksw[srcc * Dn + hc]);
    float acc = qf.x * kk.x + qf.y * kk.y + qf.z * kk.z + qf.w * kk.w;
#pragma unroll
    for (int off = 1; off < 16; off <<= 1) acc += __shfl_xor(acc, off, 64);
    if (gl == 0) myslog[TK + w] = (src >= 0) ? acc * 0.125f : NEGV;
  }
#pragma unroll 2
  for (int pass = 0; pass < 8; ++pass) {
    int s = pass * 4 + g;
    int se = s_sel[wid][s];
    float4 kk = *reinterpret_cast<const float4*>(&kcsa[se * Dn + hc]);
    float acc = qf.x * kk.x + qf.y * kk.y + qf.z * kk.z + qf.w * kk.w;
#pragma unroll
    for (int off = 1; off < 16; off <<= 1) acc += __shfl_xor(acc, off, 64);
    if (gl == 0) myslog[s] = s_ok[wid][s] ? acc * 0.125f : NEGV;
  }
  if (lane == 0) myslog[160] = sink[h];

  float x0 = myslog[lane];
  float x1 = myslog[lane + 64];
  float x2 = (lane < 33) ? myslog[lane + 128] : NEGV;
  float m = fmaxf(x0, fmaxf(x1, x2));
#pragma unroll
  for (int off = 32; off; off >>= 1) m = fmaxf(m, __shfl_xor(m, off, 64));
  float e0 = expf(x0 - m), e1 = expf(x1 - m);
  float e2 = (lane < 33) ? expf(x2 - m) : 0.f;
  float sden = e0 + e1 + e2;
#pragma unroll
  for (int off = 32; off; off >>= 1) sden += __shfl_xor(sden, off, 64);
  const float inv = 1.f / sden;
  myslog[lane] = e0 * inv;
  myslog[lane + 64] = e1 * inv;
  if (lane < 33) myslog[lane + 128] = e2 * inv;

  float4 acc = make_float4(0.f, 0.f, 0.f, 0.f);
#pragma unroll 4
  for (int pass = 0; pass < 32; ++pass) {
    int w = pass * 4 + g;
    int src = t + w - (NW - 1);
    int srcc = max(src, 0);
    float pv = myslog[TK + w];
    pv = (src >= 0) ? pv : 0.f;
    float4 vv = *reinterpret_cast<const float4*>(&kv[srcc * Dn + hc]);
    acc.x += pv * vv.x;
    acc.y += pv * vv.y;
    acc.z += pv * vv.z;
    acc.w += pv * vv.w;
  }
#pragma unroll 2
  for (int pass = 0; pass < 8; ++pass) {
    int s = pass * 4 + g;
    float pv = myslog[s];
    int se = s_sel[wid][s];
    float4 vv = *reinterpret_cast<const float4*>(&ccsa[se * Dn + hc]);
    acc.x += pv * vv.x;
    acc.y += pv * vv.y;
    acc.z += pv * vv.z;
    acc.w += pv * vv.w;
  }
  acc.x += __shfl_xor(acc.x, 16, 64);
  acc.y += __shfl_xor(acc.y, 16, 64);
  acc.z += __shfl_xor(acc.z, 16, 64);
  acc.w += __shfl_xor(acc.w, 16, 64);
  acc.x += __shfl_xor(acc.x, 32, 64);
  acc.y += __shfl_xor(acc.y, 32, 64);
  acc.z += __shfl_xor(acc.z, 32, 64);
  acc.w += __shfl_xor(acc.w, 32, 64);
  if (lane < 16) {
    float vals[4] = {acc.x, acc.y, acc.z, acc.w};
    int colb = h * Cn + lane * 4;
#pragma unroll
    for (int r = 0; r < 4; ++r) {
      int gc = colb + r;
      float v = vals[r];
      u16 hb = f2bf(v);
      u16 lb = f2bf(v - bf2f(hb));
      size_t idx = ((size_t)(gc >> 3) * 1024 + t) * 8 + (gc & 7);
      atp[idx] = hb;
      atp[idx + 524288] = lb;
    }
  }
}

// ---------------- host launcher ----------------
extern "C" void kernel_launch(void* const* d_in, const int* in_sizes, int n_in,
                              void* d_out, int out_size, void* d_ws,
                              size_t ws_size, hipStream_t stream) {
  const float* h = (const float*)d_in[0];
  const int* mask = (const int*)d_in[1];
  const int* tok = (const int*)d_in[2];
  const int* endp = (const int*)d_in[3];
  const float* W_dq = (const float*)d_in[5];
  const float* W_uq = (const float*)d_in[6];
  const float* W_csa_kv = (const float*)d_in[7];
  const float* W_csa_z = (const float*)d_in[8];
  const float* B_csa = (const float*)d_in[9];
  const float* W_idx_kv = (const float*)d_in[10];
  const float* W_idx_z = (const float*)d_in[11];
  const float* B_idx = (const float*)d_in[12];
  const float* W_iuq = (const float*)d_in[13];
  const float* W_w = (const float*)d_in[14];
  const float* W_swkv = (const float*)d_in[15];
  const float* qnw = (const float*)d_in[16];
  const float* knw = (const float*)d_in[17];
  const float* W_o = (const float*)d_in[18];
  const float* sink = (const float*)d_in[19];

  float* ws = (float*)d_ws;
  u16* hA = (u16*)(ws + 0);
  float* qbuf = ws + 0;
  u16* qlP = (u16*)(ws + 524288);
  float* hckv = ws + 786432;
  u16* atP = (u16*)(ws + 786432);
  float* hcz = ws + 1310720;
  float* kvb = ws + 1835008;
  float* hikv = ws + 2359296;
  float* hiz = ws + 2424832;
  float* q_lat = ws + 2490368;
  float* ccsa = ws + 2752512;
  float* kcsa = ws + 2818048;
  float* kidx = ws + 2883584;
  int* seli = (int*)(ws + 2891776);
  int* selok = (int*)(ws + 2924544);
  float* qib = ws + 2957312;
  float* kswb = ws + 3088384;
  u16* pW = (u16*)(ws + 3612672);
  u16* pWdq = pW;
  u16* pWckv = pW + 262144;
  u16* pWcz = pW + 786432;
  u16* pWsw = pW + 1310720;
  u16* pWuq = pW + 1835008;
  u16* pWo = pW + 2097152;
  float* outp = (float*)d_out;

  // ---- pack all GEMM operands to split bf16 ----
  {
    PackJobs pj{};
    const float* srcs[7] = {h, W_dq, W_csa_kv, W_csa_z, W_swkv, W_uq, W_o};
    u16* dsts[7] = {hA, pWdq, pWckv, pWcz, pWsw, pWuq, pWo};
    int Ns[7] = {0, 256, 512, 512, 512, 512, 512};
    int logNs[7] = {0, 8, 9, 9, 9, 9, 9};
    int Ks[7] = {512, 512, 512, 512, 512, 256, 512};
    int isA[7] = {1, 0, 0, 0, 0, 0, 0};
    int pss[7] = {524288, 131072, 262144, 262144, 262144, 131072, 262144};
    int s = 0;
    for (int i = 0; i < 7; ++i) {
      pj.src[i] = srcs[i];
      pj.dst[i] = dsts[i];
      pj.N[i] = Ns[i];
      pj.logN[i] = logNs[i];
      pj.isA[i] = isA[i];
      pj.ps[i] = pss[i];
      pj.start[i] = s;
      s += isA[i] ? 1024 * (Ks[i] / 8) : (Ks[i] / 8) * Ns[i];
    }
    pj.start[7] = s;
    pack_all<<<(s + 255) / 256, 256, 0, stream>>>(pj);
  }

  auto normTile = [](const u16* pB, int N, int n0, float* C, int ldc, int bps) {
    TileDesc td{};
    td.Blo = pB + n0 * 8;
    td.Bhi = pB + (n0 + 64) * 8;
    td.ldNlo = td.ldNhi = N;
    td.Clo = C + n0;
    td.Chi = C + n0 + 64;
    td.ldClo = td.ldChi = ldc;
    td.mode = 0;
    td.bps = bps;
    return td;
  };

  // ---- K1: h @ {W_dq(mode2), W_csa_kv, W_csa_z, W_swkv} (MT=64 tiles) ----
  {
    GemmArgs ga{};
    int nt = 0;
    for (int n0 = 0; n0 < 256; n0 += 128) {
      TileDesc td = normTile(pWdq, 256, n0, q_lat, 256, 131072);
      td.mode = 2;
      td.Cp = qlP;
      td.cpps = 262144;
      td.n0 = n0;
      ga.d[nt++] = td;
    }
    for (int n0 = 0; n0 < 512; n0 += 128) ga.d[nt++] = normTile(pWckv, 512, n0, hckv, 512, 262144);
    for (int n0 = 0; n0 < 512; n0 += 128) ga.d[nt++] = normTile(pWcz, 512, n0, hcz, 512, 262144);
    for (int n0 = 0; n0 < 512; n0 += 128) ga.d[nt++] = normTile(pWsw, 512, n0, kvb, 512, 262144);
    gemm_bf16<2><<<dim3(nt, 16), 256, 0, stream>>>(hA, 16, 524288, ga);
  }
  // ---- K2: q_lat @ W_uq -> qbuf ----
  {
    GemmArgs ga{};
    int nt = 0;
    for (int n0 = 0; n0 < 512; n0 += 128) ga.d[nt++] = normTile(pWuq, 512, n0, qbuf, 512, 131072);
    gemm_bf16<2><<<dim3(nt, 16), 256, 0, stream>>>(qlP, 8, 262144, ga);
  }
  // ---- fp32 idx-path GEMMs (4 tokens/block) ----
  idx_kernel<<<Tn / 4, 256, 0, stream>>>(h, q_lat, W_idx_kv, W_idx_z, W_iuq,
                                         hikv, hiz, qib);
  // ---- merged phrase aggregation + q/k_sw rms+rope ----
  phrase_rope_kernel<<<Pn + Tn, 512, 0, stream>>>(
      mask, tok, endp, hckv, hcz, hikv, hiz, B_csa, B_idx, knw, qnw, ccsa,
      kcsa, kidx, qbuf, kvb, kswb);
  // ---- scores + top-32 ----
  score_topk_kernel<<<Tn, 128, 0, stream>>>(h, W_w, qib, kidx, endp, seli,
                                            selok);
  // ---- attention v4 (4 consecutive t per block, one head) ----
  attn4_kernel<<<dim3(Tn / 4 * Hn), 256, 0, stream>>>(qbuf, kswb, kvb, kcsa,
                                                      ccsa, seli, selok, sink,
                                                      atP);
  // ---- K7: attno @ W_o -> out ----
  {
    GemmArgs ga{};
    int nt = 0;
    for (int n0 = 0; n0 < 512; n0 += 128) ga.d[nt++] = normTile(pWo, 512, n0, outp, 512, 262144);
    gemm_bf16<2><<<dim3(nt, 16), 256, 0, stream>>>(atP, 16, 524288, ga);
  }
  (void)in_sizes; (void)n_in; (void)out_size; (void)ws_size;
}

// Round 9
// 126.488 us; speedup vs baseline: 1.4606x; 1.0796x over previous
//
#include <hip/hip_runtime.h>
#include <cmath>

// ---------------- constants (match reference) ----------------
static constexpr int Tn = 1024, Dn = 512, Hn = 8, Cn = 64, DQn = 256,
                     NIn = 2, CIn = 64, TK = 32, LM = 16, NW = 128, Pn = 128;
#define NEGV (-1e30f)

typedef unsigned short u16;
typedef __bf16 bf16x8 __attribute__((ext_vector_type(8)));
typedef float f32x4 __attribute__((ext_vector_type(4)));

__device__ __forceinline__ u16 f2bf(float x) {
  unsigned u = __float_as_uint(x);
  return (u16)((u + 0x7fffu + ((u >> 16) & 1u)) >> 16);
}
__device__ __forceinline__ float bf2f(u16 b) {
  return __uint_as_float((unsigned)b << 16);
}

// ---------------- pack: fp32 -> split bf16 (hi+lo), k-grouped-by-8 ----------
struct PackJobs {
  const float* src[7];
  u16* dst[7];
  int start[8];
  int N[7];
  int logN[7];
  int isA[7];
  int ps[7];  // plane size in u16 elements
};

__global__ __launch_bounds__(256) void pack_all(PackJobs pj) {
  int i = blockIdx.x * 256 + threadIdx.x;
  if (i >= pj.start[7]) return;
  int j = 0;
  while (i >= pj.start[j + 1]) ++j;
  int local = i - pj.start[j];
  const float* s = pj.src[j];
  u16* dh = pj.dst[j];
  u16* dl = dh + pj.ps[j];
  float x[8];
  size_t idx;
  if (pj.isA[j]) {
    int m = local & 1023;
    int kg = local >> 10;
    const float4* p = reinterpret_cast<const float4*>(s + (size_t)m * 512 + kg * 8);
    float4 a = p[0], b = p[1];
    x[0] = a.x; x[1] = a.y; x[2] = a.z; x[3] = a.w;
    x[4] = b.x; x[5] = b.y; x[6] = b.z; x[7] = b.w;
    idx = ((size_t)kg * 1024 + m) * 8;
  } else {
    int N = pj.N[j];
    int n = local & (N - 1);
    int kg = local >> pj.logN[j];
#pragma unroll
    for (int e = 0; e < 8; ++e) x[e] = s[(size_t)(kg * 8 + e) * N + n];
    idx = ((size_t)kg * N + n) * 8;
  }
  union { u16 u[8]; int4 v; } oh, ol;
#pragma unroll
  for (int e = 0; e < 8; ++e) {
    u16 hb = f2bf(x[e]);
    oh.u[e] = hb;
    ol.u[e] = f2bf(x[e] - bf2f(hb));
  }
  *reinterpret_cast<int4*>(dh + idx) = oh.v;
  *reinterpret_cast<int4*>(dl + idx) = ol.v;
}

// ---------------- split-bf16 MFMA GEMM (templated M-tile) ----------------
struct TileDesc {
  const u16* Blo;
  const u16* Bhi;
  float* Clo;
  float* Chi;
  u16* Cp;
  int ldNlo, ldNhi, ldClo, ldChi, mode, n0, bps, cpps;
};
struct GemmArgs {
  TileDesc d[15];
};

#define GLD16(gp, lp)                                                     \
  __builtin_amdgcn_global_load_lds(                                      \
      (const __attribute__((address_space(1))) unsigned int*)(gp),       \
      (__attribute__((address_space(3))) unsigned int*)(lp), 16, 0, 0)

template <int FMW>
__global__ __launch_bounds__(256) void gemm_bf16(const u16* __restrict__ Ap,
                                                 int NK, int aps, GemmArgs ga) {
  constexpr int MT = FMW * 32;
  const int ct = blockIdx.x, rt = blockIdx.y;
  const TileDesc d = ga.d[ct];
  const int m0 = rt * MT;
  __shared__ __align__(16) u16 lA[2][2][4][MT][8];
  __shared__ __align__(16) u16 lB[2][2][4][128][8];
  const int tid = threadIdx.x;
  const int w = tid >> 6, lane = tid & 63;
  const int wm = w >> 1, wn = w & 1;

  f32x4 acc[FMW][4];
#pragma unroll
  for (int a = 0; a < FMW; ++a)
#pragma unroll
    for (int b = 0; b < 4; ++b)
#pragma unroll
      for (int r = 0; r < 4; ++r) acc[a][b][r] = 0.f;

  auto stage = [&](int buf, int kg) {
#pragma unroll
    for (int r0 = 0; r0 < MT; r0 += 64) {
      GLD16(Ap + ((size_t)kg * 1024 + m0 + r0 + lane) * 8, &lA[buf][0][w][r0][0]);
      GLD16(Ap + aps + ((size_t)kg * 1024 + m0 + r0 + lane) * 8, &lA[buf][1][w][r0][0]);
    }
    GLD16(d.Blo + ((size_t)kg * d.ldNlo + lane) * 8, &lB[buf][0][w][0][0]);
    GLD16(d.Bhi + ((size_t)kg * d.ldNhi + lane) * 8, &lB[buf][0][w][64][0]);
    GLD16(d.Blo + d.bps + ((size_t)kg * d.ldNlo + lane) * 8, &lB[buf][1][w][0][0]);
    GLD16(d.Bhi + d.bps + ((size_t)kg * d.ldNhi + lane) * 8, &lB[buf][1][w][64][0]);
  };

  stage(0, w);
  const int kq = lane >> 4, fr = lane & 15;
  for (int ks = 0; ks < NK; ++ks) {
    __syncthreads();
    if (ks + 1 < NK) stage((ks + 1) & 1, (ks + 1) * 4 + w);
    const int cb = ks & 1;
    bf16x8 aFh[FMW], aFl[FMW], bFh[4], bFl[4];
#pragma unroll
    for (int f = 0; f < FMW; ++f) {
      aFh[f] = *reinterpret_cast<const bf16x8*>(&lA[cb][0][kq][wm * (FMW * 16) + f * 16 + fr][0]);
      aFl[f] = *reinterpret_cast<const bf16x8*>(&lA[cb][1][kq][wm * (FMW * 16) + f * 16 + fr][0]);
    }
#pragma unroll
    for (int f = 0; f < 4; ++f) {
      bFh[f] = *reinterpret_cast<const bf16x8*>(&lB[cb][0][kq][wn * 64 + f * 16 + fr][0]);
      bFl[f] = *reinterpret_cast<const bf16x8*>(&lB[cb][1][kq][wn * 64 + f * 16 + fr][0]);
    }
#pragma unroll
    for (int fm = 0; fm < FMW; ++fm)
#pragma unroll
      for (int fn = 0; fn < 4; ++fn) {
        acc[fm][fn] = __builtin_amdgcn_mfma_f32_16x16x32_bf16(aFh[fm], bFh[fn],
                                                              acc[fm][fn], 0, 0, 0);
        acc[fm][fn] = __builtin_amdgcn_mfma_f32_16x16x32_bf16(aFl[fm], bFh[fn],
                                                              acc[fm][fn], 0, 0, 0);
        acc[fm][fn] = __builtin_amdgcn_mfma_f32_16x16x32_bf16(aFh[fm], bFl[fn],
                                                              acc[fm][fn], 0, 0, 0);
      }
  }
  float* Cb = (wn == 0) ? d.Clo : d.Chi;
  const int ldc = (wn == 0) ? d.ldClo : d.ldChi;
  if (d.mode != 1) {
#pragma unroll
    for (int fm = 0; fm < FMW; ++fm)
#pragma unroll
      for (int fn = 0; fn < 4; ++fn)
#pragma unroll
        for (int r = 0; r < 4; ++r) {
          int row = m0 + wm * (FMW * 16) + fm * 16 + (lane >> 4) * 4 + r;
          int cl = fn * 16 + fr;
          Cb[(size_t)row * ldc + cl] = acc[fm][fn][r];
        }
  }
  if (d.mode >= 1) {
#pragma unroll
    for (int fm = 0; fm < FMW; ++fm)
#pragma unroll
      for (int fn = 0; fn < 4; ++fn)
#pragma unroll
        for (int r = 0; r < 4; ++r) {
          int row = m0 + wm * (FMW * 16) + fm * 16 + (lane >> 4) * 4 + r;
          int gc = d.n0 + wn * 64 + fn * 16 + fr;
          float v = acc[fm][fn][r];
          u16 hb = f2bf(v);
          u16 lb = f2bf(v - bf2f(hb));
          size_t idx = ((size_t)(gc >> 3) * 1024 + row) * 8 + (gc & 7);
          d.Cp[idx] = hb;
          d.Cp[idx + d.cpps] = lb;
        }
  }
}

// ---------------- merged K2 (q_lat@W_uq, MT=64 MFMA) + fp32 idx GEMMs ------
// blocks [0,64): gemm tiles (ct = bid&3, rt = bid>>2), NK=8.
// blocks [64,320): idx path, 4 tokens per block.
struct GemmSh {
  u16 lA[2][2][4][64][8];
  u16 lB[2][2][4][128][8];
};
struct IdxSh {
  float hs[4][Dn];
  float ql[4][DQn];
};

__global__ __launch_bounds__(256) void k2idx_kernel(
    const u16* __restrict__ Ap, int aps, GemmArgs ga,
    const float* __restrict__ h, const float* __restrict__ q_lat,
    const float* __restrict__ Wikv, const float* __restrict__ Wiz,
    const float* __restrict__ Wiuq, float* __restrict__ hikv,
    float* __restrict__ hiz, float* __restrict__ qib) {
  __shared__ __align__(16) char smraw[sizeof(GemmSh)];
  const int bid = blockIdx.x;
  const int tid = threadIdx.x;

  if (bid < 64) {
    // ---- GEMM path (FMW=2, MT=64, NK=8) ----
    GemmSh* sh = reinterpret_cast<GemmSh*>(smraw);
    const int ct = bid & 3, rt = bid >> 2;
    const TileDesc d = ga.d[ct];
    const int m0 = rt * 64;
    const int w = tid >> 6, lane = tid & 63;
    const int wm = w >> 1, wn = w & 1;
    constexpr int NK = 8;

    f32x4 acc[2][4];
#pragma unroll
    for (int a = 0; a < 2; ++a)
#pragma unroll
      for (int b = 0; b < 4; ++b)
#pragma unroll
        for (int r = 0; r < 4; ++r) acc[a][b][r] = 0.f;

    auto stage = [&](int buf, int kg) {
      GLD16(Ap + ((size_t)kg * 1024 + m0 + lane) * 8, &sh->lA[buf][0][w][0][0]);
      GLD16(Ap + aps + ((size_t)kg * 1024 + m0 + lane) * 8, &sh->lA[buf][1][w][0][0]);
      GLD16(d.Blo + ((size_t)kg * d.ldNlo + lane) * 8, &sh->lB[buf][0][w][0][0]);
      GLD16(d.Bhi + ((size_t)kg * d.ldNhi + lane) * 8, &sh->lB[buf][0][w][64][0]);
      GLD16(d.Blo + d.bps + ((size_t)kg * d.ldNlo + lane) * 8, &sh->lB[buf][1][w][0][0]);
      GLD16(d.Bhi + d.bps + ((size_t)kg * d.ldNhi + lane) * 8, &sh->lB[buf][1][w][64][0]);
    };

    stage(0, w);
    const int kq = lane >> 4, fr = lane & 15;
    for (int ks = 0; ks < NK; ++ks) {
      __syncthreads();
      if (ks + 1 < NK) stage((ks + 1) & 1, (ks + 1) * 4 + w);
      const int cb = ks & 1;
      bf16x8 aFh[2], aFl[2], bFh[4], bFl[4];
#pragma unroll
      for (int f = 0; f < 2; ++f) {
        aFh[f] = *reinterpret_cast<const bf16x8*>(&sh->lA[cb][0][kq][wm * 32 + f * 16 + fr][0]);
        aFl[f] = *reinterpret_cast<const bf16x8*>(&sh->lA[cb][1][kq][wm * 32 + f * 16 + fr][0]);
      }
#pragma unroll
      for (int f = 0; f < 4; ++f) {
        bFh[f] = *reinterpret_cast<const bf16x8*>(&sh->lB[cb][0][kq][wn * 64 + f * 16 + fr][0]);
        bFl[f] = *reinterpret_cast<const bf16x8*>(&sh->lB[cb][1][kq][wn * 64 + f * 16 + fr][0]);
      }
#pragma unroll
      for (int fm = 0; fm < 2; ++fm)
#pragma unroll
        for (int fn = 0; fn < 4; ++fn) {
          acc[fm][fn] = __builtin_amdgcn_mfma_f32_16x16x32_bf16(aFh[fm], bFh[fn],
                                                                acc[fm][fn], 0, 0, 0);
          acc[fm][fn] = __builtin_amdgcn_mfma_f32_16x16x32_bf16(aFl[fm], bFh[fn],
                                                                acc[fm][fn], 0, 0, 0);
          acc[fm][fn] = __builtin_amdgcn_mfma_f32_16x16x32_bf16(aFh[fm], bFl[fn],
                                                                acc[fm][fn], 0, 0, 0);
        }
    }
    float* Cb = (wn == 0) ? d.Clo : d.Chi;
    const int ldc = (wn == 0) ? d.ldClo : d.ldChi;
#pragma unroll
    for (int fm = 0; fm < 2; ++fm)
#pragma unroll
      for (int fn = 0; fn < 4; ++fn)
#pragma unroll
        for (int r = 0; r < 4; ++r) {
          int row = m0 + wm * 32 + fm * 16 + (lane >> 4) * 4 + r;
          int cl = fn * 16 + fr;
          Cb[(size_t)row * ldc + cl] = acc[fm][fn][r];
        }
    return;
  }

  // ---- idx path ----
  IdxSh* sh = reinterpret_cast<IdxSh*>(smraw);
  const int t0 = (bid - 64) * 4;
  for (int i = tid; i < 4 * Dn; i += 256)
    sh->hs[i >> 9][i & 511] = h[(size_t)(t0 + (i >> 9)) * Dn + (i & 511)];
  for (int i = tid; i < 4 * DQn; i += 256)
    sh->ql[i >> 8][i & 255] = q_lat[(size_t)(t0 + (i >> 8)) * DQn + (i & 255)];
  __syncthreads();
  if (tid < 128) {
    const float* Wm = (tid < 64) ? Wikv : Wiz;
    const int ci = tid & 63;
    float a0 = 0.f, a1 = 0.f, a2 = 0.f, a3 = 0.f;
#pragma unroll 8
    for (int k = 0; k < Dn; ++k) {
      float wv = Wm[k * CIn + ci];
      a0 += sh->hs[0][k] * wv;
      a1 += sh->hs[1][k] * wv;
      a2 += sh->hs[2][k] * wv;
      a3 += sh->hs[3][k] * wv;
    }
    float* dst = (tid < 64) ? hikv : hiz;
    dst[(size_t)(t0 + 0) * CIn + ci] = a0;
    dst[(size_t)(t0 + 1) * CIn + ci] = a1;
    dst[(size_t)(t0 + 2) * CIn + ci] = a2;
    dst[(size_t)(t0 + 3) * CIn + ci] = a3;
  } else {
    const int jj = tid - 128;
    float a0 = 0.f, a1 = 0.f, a2 = 0.f, a3 = 0.f;
#pragma unroll 8
    for (int k = 0; k < DQn; ++k) {
      float wv = Wiuq[k * 128 + jj];
      a0 += sh->ql[0][k] * wv;
      a1 += sh->ql[1][k] * wv;
      a2 += sh->ql[2][k] * wv;
      a3 += sh->ql[3][k] * wv;
    }
    qib[(size_t)(t0 + 0) * 128 + jj] = a0;
    qib[(size_t)(t0 + 1) * 128 + jj] = a1;
    qib[(size_t)(t0 + 2) * 128 + jj] = a2;
    qib[(size_t)(t0 + 3) * 128 + jj] = a3;
  }
}

// ---------------- merged phrase aggregation + RMS/RoPE ----------------
__global__ __launch_bounds__(512) void phrase_rope_kernel(
    const int* __restrict__ maskbuf, const int* __restrict__ tokbuf,
    const int* __restrict__ endbuf, const float* __restrict__ hckv,
    const float* __restrict__ hcz, const float* __restrict__ hikv,
    const float* __restrict__ hiz, const float* __restrict__ Bcsa,
    const float* __restrict__ Bidx, const float* __restrict__ knw,
    const float* __restrict__ qnw, float* __restrict__ ccsa,
    float* __restrict__ kcsa, float* __restrict__ kidx,
    float* __restrict__ q, const float* __restrict__ kv,
    float* __restrict__ ksw) {
  const int tid = threadIdx.x;
  const int c = tid & 63;
  const float sgn = (c < 32) ? -1.f : 1.f;

  if (blockIdx.x >= Pn) {
    const int t = blockIdx.x - Pn;
    const float fr = (float)t * powf(10000.0f, -(float)(c & 31) / 32.0f);
    const float cv = cosf(fr), sv = sinf(fr);
    {
      float x = q[t * Dn + tid];
      float ss = x * x;
#pragma unroll
      for (int off = 32; off; off >>= 1) ss += __shfl_xor(ss, off, 64);
      float xr = x * rsqrtf(ss / (float)Cn + 1e-6f) * qnw[c];
      float pr = __shfl_xor(xr, 32, 64);
      q[t * Dn + tid] = xr * cv + sgn * pr * sv;
    }
    {
      float y = kv[t * Dn + tid];
      float ss = y * y;
#pragma unroll
      for (int off = 32; off; off >>= 1) ss += __shfl_xor(ss, off, 64);
      float yr = y * rsqrtf(ss / (float)Cn + 1e-6f) * knw[c];
      float pr = __shfl_xor(yr, 32, 64);
      ksw[t * Dn + tid] = yr * cv + sgn * pr * sv;
    }
    return;
  }

  const int p = blockIdx.x;
  __shared__ int s_bytemode;
  __shared__ int s_tok[LM];
  __shared__ int s_m[LM];
  __shared__ int s_pos, s_anyv;

  if (tid == 0) s_bytemode = 0;
  __syncthreads();
  {
    unsigned wv = ((const unsigned*)maskbuf)[tid];
    if (wv > 1u) atomicOr(&s_bytemode, 1);
  }
  __syncthreads();
  const int bytemode = s_bytemode;
  if (tid < LM) {
    int mv;
    if (bytemode)
      mv = ((const unsigned char*)maskbuf)[p * LM + tid] != 0;
    else
      mv = maskbuf[p * LM + tid] != 0;
    s_m[tid] = mv;
    s_tok[tid] = tokbuf[p * LM + tid];
  }
  if (tid == 0) {
    int e = endbuf[p];
    s_pos = min(max(e, 0), Tn - 1);
  }
  __syncthreads();
  if (tid == 0) {
    int any = 0;
    for (int l = 0; l < LM; ++l) any |= s_m[l];
    s_anyv = any;
  }
  __syncthreads();
  const int anyv = s_anyv;
  const int pos = s_pos;
  const float fr = (float)pos * powf(10000.0f, -(float)(c & 31) / 32.0f);
  const float cv = cosf(fr), sv = sinf(fr);

  {
    float z[LM];
    float zmax = NEGV;
#pragma unroll
    for (int l = 0; l < LM; ++l) {
      float zv = hcz[s_tok[l] * Dn + tid] + Bcsa[l * (Hn * Cn) + tid];
      zv = s_m[l] ? zv : NEGV;
      z[l] = zv;
      zmax = fmaxf(zmax, zv);
    }
    float den = 0.f, num = 0.f;
#pragma unroll
    for (int l = 0; l < LM; ++l) {
      float e = expf(z[l] - zmax);
      den += e;
      num += e * hckv[s_tok[l] * Dn + tid];
    }
    float cc = anyv ? (num / den) : 0.f;
    ccsa[p * (Hn * Cn) + tid] = cc;

    float ss = cc * cc;
#pragma unroll
    for (int off = 32; off; off >>= 1) ss += __shfl_xor(ss, off, 64);
    float kn = cc * rsqrtf(ss / (float)Cn + 1e-6f) * knw[c];
    float pr = __shfl_xor(kn, 32, 64);
    kcsa[p * (Hn * Cn) + tid] = kn * cv + sgn * pr * sv;
  }

  if (tid < CIn) {
    float zk[LM];
    float zm = NEGV;
#pragma unroll
    for (int l = 0; l < LM; ++l) {
      float zv = hiz[s_tok[l] * CIn + tid] + Bidx[l * CIn + tid];
      zv = s_m[l] ? zv : NEGV;
      zk[l] = zv;
      zm = fmaxf(zm, zv);
    }
    float dk = 0.f, nk = 0.f;
#pragma unroll
    for (int l = 0; l < LM; ++l) {
      float e = expf(zk[l] - zm);
      dk += e;
      nk += e * hikv[s_tok[l] * CIn + tid];
    }
    float ki = anyv ? (nk / dk) : 0.f;
    float pr = __shfl_xor(ki, 32, 64);
    kidx[p * CIn + tid] = ki * cv + sgn * pr * sv;
  }
}

// ---------------- phrase scores + top-32 (fp32, LDS-transposed kidx) --------
__global__ __launch_bounds__(128) void score_topk_kernel(
    const float* __restrict__ hbuf, const float* __restrict__ Ww,
    const float* __restrict__ qi, const float* __restrict__ kidx,
    const int* __restrict__ endbuf, int* __restrict__ sel,
    int* __restrict__ selok) {
  const int t = blockIdx.x;
  const int tid = threadIdx.x;
  __shared__ float sqi[NIn * CIn];
  __shared__ float kT[CIn][Pn + 1];
  __shared__ float sI[Pn];
  __shared__ float sp0[128], sp1[128];

  sqi[tid] = qi[(size_t)t * (NIn * CIn) + tid];
#pragma unroll
  for (int it = 0; it < 16; ++it) {
    int idx4 = it * 128 + tid;
    float4 v = reinterpret_cast<const float4*>(kidx)[idx4];
    int p = idx4 >> 4;
    int c4 = (idx4 & 15) * 4;
    kT[c4 + 0][p] = v.x;
    kT[c4 + 1][p] = v.y;
    kT[c4 + 2][p] = v.z;
    kT[c4 + 3][p] = v.w;
  }
  float p0 = 0.f, p1 = 0.f;
#pragma unroll
  for (int e4 = 0; e4 < 4; ++e4) {
    int e = tid * 4 + e4;
    float hv = hbuf[(size_t)t * Dn + e];
    p0 += hv * Ww[e * NIn + 0];
    p1 += hv * Ww[e * NIn + 1];
  }
  sp0[tid] = p0;
  sp1[tid] = p1;
  __syncthreads();
  for (int srd = 64; srd; srd >>= 1) {
    if (tid < srd) {
      sp0[tid] += sp0[tid + srd];
      sp1[tid] += sp1[tid + srd];
    }
    __syncthreads();
  }
  const float ww0 = sp0[0], ww1 = sp1[0];

  {
    const int p = tid;
    float s0 = 0.f, s1 = 0.f;
#pragma unroll 16
    for (int ci = 0; ci < CIn; ++ci) {
      float kc = kT[ci][p];
      s0 += sqi[ci] * kc;
      s1 += sqi[CIn + ci] * kc;
    }
    float Iv = fmaxf(s0, 0.f) * ww0 + fmaxf(s1, 0.f) * ww1;
    int e = endbuf[p];
    if (!(e <= t && e >= 0)) Iv = NEGV;
    sI[p] = Iv;
  }
  __syncthreads();

  if (tid < 64) {
    float v0 = sI[tid], v1 = sI[tid + 64];
    for (int it = 0; it < TK; ++it) {
      float bv;
      int bi;
      if (v0 >= v1) { bv = v0; bi = tid; } else { bv = v1; bi = tid + 64; }
#pragma unroll
      for (int off = 32; off; off >>= 1) {
        float ov = __shfl_xor(bv, off, 64);
        int oi = __shfl_xor(bi, off, 64);
        if (ov > bv || (ov == bv && oi < bi)) { bv = ov; bi = oi; }
      }
      if (tid == 0) {
        sel[t * TK + it] = bi;
        selok[t * TK + it] = (bv > NEGV * 0.5f) ? 1 : 0;
      }
      if (bi == tid) v0 = -3.4e38f;
      if (bi == tid + 64) v1 = -3.4e38f;
    }
  }
}

// ---------------- attention v5: 8 consecutive t per block (L1 reuse x8) -----
__global__ __launch_bounds__(512) void attn8_kernel(
    const float* __restrict__ q, const float* __restrict__ ksw,
    const float* __restrict__ kv, const float* __restrict__ kcsa,
    const float* __restrict__ ccsa, const int* __restrict__ sel,
    const int* __restrict__ selok, const float* __restrict__ sink,
    u16* __restrict__ atp) {
  const int tid = threadIdx.x;
  const int wid = tid >> 6, lane = tid & 63;
  const int g = lane >> 4;
  const int gl = lane & 15;
  const int h = blockIdx.x >> 7;
  const int t = ((blockIdx.x & 127) << 3) + wid;

  __shared__ float slog[8][164];
  __shared__ int s_sel[8][TK];
  __shared__ int s_ok[8][TK];

  if (lane < TK) {
    s_sel[wid][lane] = sel[t * TK + lane];
    s_ok[wid][lane] = selok[t * TK + lane];
  }
  const int hc = h * Cn + gl * 4;
  const float4 qf = *reinterpret_cast<const float4*>(&q[t * Dn + hc]);
  float* myslog = slog[wid];

#pragma unroll 4
  for (int pass = 0; pass < 32; ++pass) {
    int w = pass * 4 + g;
    int src = t + w - (NW - 1);
    int srcc = max(src, 0);
    float4 kk = *reinterpret_cast<const float4*>(&ksw[srcc * Dn + hc]);
    float acc = qf.x * kk.x + qf.y * kk.y + qf.z * kk.z + qf.w * kk.w;
#pragma unroll
    for (int off = 1; off < 16; off <<= 1) acc += __shfl_xor(acc, off, 64);
    if (gl == 0) myslog[TK + w] = (src >= 0) ? acc * 0.125f : NEGV;
  }
#pragma unroll 2
  for (int pass = 0; pass < 8; ++pass) {
    int s = pass * 4 + g;
    int se = s_sel[wid][s];
    float4 kk = *reinterpret_cast<const float4*>(&kcsa[se * Dn + hc]);
    float acc = qf.x * kk.x + qf.y * kk.y + qf.z * kk.z + qf.w * kk.w;
#pragma unroll
    for (int off = 1; off < 16; off <<= 1) acc += __shfl_xor(acc, off, 64);
    if (gl == 0) myslog[s] = s_ok[wid][s] ? acc * 0.125f : NEGV;
  }
  if (lane == 0) myslog[160] = sink[h];

  float x0 = myslog[lane];
  float x1 = myslog[lane + 64];
  float x2 = (lane < 33) ? myslog[lane + 128] : NEGV;
  float m = fmaxf(x0, fmaxf(x1, x2));
#pragma unroll
  for (int off = 32; off; off >>= 1) m = fmaxf(m, __shfl_xor(m, off, 64));
  float e0 = expf(x0 - m), e1 = expf(x1 - m);
  float e2 = (lane < 33) ? expf(x2 - m) : 0.f;
  float sden = e0 + e1 + e2;
#pragma unroll
  for (int off = 32; off; off >>= 1) sden += __shfl_xor(sden, off, 64);
  const float inv = 1.f / sden;
  myslog[lane] = e0 * inv;
  myslog[lane + 64] = e1 * inv;
  if (lane < 33) myslog[lane + 128] = e2 * inv;

  float4 acc = make_float4(0.f, 0.f, 0.f, 0.f);
#pragma unroll 4
  for (int pass = 0; pass < 32; ++pass) {
    int w = pass * 4 + g;
    int src = t + w - (NW - 1);
    int srcc = max(src, 0);
    float pv = myslog[TK + w];
    pv = (src >= 0) ? pv : 0.f;
    float4 vv = *reinterpret_cast<const float4*>(&kv[srcc * Dn + hc]);
    acc.x += pv * vv.x;
    acc.y += pv * vv.y;
    acc.z += pv * vv.z;
    acc.w += pv * vv.w;
  }
#pragma unroll 2
  for (int pass = 0; pass < 8; ++pass) {
    int s = pass * 4 + g;
    float pv = myslog[s];
    int se = s_sel[wid][s];
    float4 vv = *reinterpret_cast<const float4*>(&ccsa[se * Dn + hc]);
    acc.x += pv * vv.x;
    acc.y += pv * vv.y;
    acc.z += pv * vv.z;
    acc.w += pv * vv.w;
  }
  acc.x += __shfl_xor(acc.x, 16, 64);
  acc.y += __shfl_xor(acc.y, 16, 64);
  acc.z += __shfl_xor(acc.z, 16, 64);
  acc.w += __shfl_xor(acc.w, 16, 64);
  acc.x += __shfl_xor(acc.x, 32, 64);
  acc.y += __shfl_xor(acc.y, 32, 64);
  acc.z += __shfl_xor(acc.z, 32, 64);
  acc.w += __shfl_xor(acc.w, 32, 64);
  if (lane < 16) {
    float vals[4] = {acc.x, acc.y, acc.z, acc.w};
    int colb = h * Cn + lane * 4;
#pragma unroll
    for (int r = 0; r < 4; ++r) {
      int gc = colb + r;
      float v = vals[r];
      u16 hb = f2bf(v);
      u16 lb = f2bf(v - bf2f(hb));
      size_t idx = ((size_t)(gc >> 3) * 1024 + t) * 8 + (gc & 7);
      atp[idx] = hb;
      atp[idx + 524288] = lb;
    }
  }
}

// ---------------- host launcher ----------------
extern "C" void kernel_launch(void* const* d_in, const int* in_sizes, int n_in,
                              void* d_out, int out_size, void* d_ws,
                              size_t ws_size, hipStream_t stream) {
  const float* h = (const float*)d_in[0];
  const int* mask = (const int*)d_in[1];
  const int* tok = (const int*)d_in[2];
  const int* endp = (const int*)d_in[3];
  const float* W_dq = (const float*)d_in[5];
  const float* W_uq = (const float*)d_in[6];
  const float* W_csa_kv = (const float*)d_in[7];
  const float* W_csa_z = (const float*)d_in[8];
  const float* B_csa = (const float*)d_in[9];
  const float* W_idx_kv = (const float*)d_in[10];
  const float* W_idx_z = (const float*)d_in[11];
  const float* B_idx = (const float*)d_in[12];
  const float* W_iuq = (const float*)d_in[13];
  const float* W_w = (const float*)d_in[14];
  const float* W_swkv = (const float*)d_in[15];
  const float* qnw = (const float*)d_in[16];
  const float* knw = (const float*)d_in[17];
  const float* W_o = (const float*)d_in[18];
  const float* sink = (const float*)d_in[19];

  float* ws = (float*)d_ws;
  u16* hA = (u16*)(ws + 0);
  float* qbuf = ws + 0;
  u16* qlP = (u16*)(ws + 524288);
  float* hckv = ws + 786432;
  u16* atP = (u16*)(ws + 786432);
  float* hcz = ws + 1310720;
  float* kvb = ws + 1835008;
  float* hikv = ws + 2359296;
  float* hiz = ws + 2424832;
  float* q_lat = ws + 2490368;
  float* ccsa = ws + 2752512;
  float* kcsa = ws + 2818048;
  float* kidx = ws + 2883584;
  int* seli = (int*)(ws + 2891776);
  int* selok = (int*)(ws + 2924544);
  float* qib = ws + 2957312;
  float* kswb = ws + 3088384;
  u16* pW = (u16*)(ws + 3612672);
  u16* pWdq = pW;
  u16* pWckv = pW + 262144;
  u16* pWcz = pW + 786432;
  u16* pWsw = pW + 1310720;
  u16* pWuq = pW + 1835008;
  u16* pWo = pW + 2097152;
  float* outp = (float*)d_out;

  // ---- pack all GEMM operands to split bf16 ----
  {
    PackJobs pj{};
    const float* srcs[7] = {h, W_dq, W_csa_kv, W_csa_z, W_swkv, W_uq, W_o};
    u16* dsts[7] = {hA, pWdq, pWckv, pWcz, pWsw, pWuq, pWo};
    int Ns[7] = {0, 256, 512, 512, 512, 512, 512};
    int logNs[7] = {0, 8, 9, 9, 9, 9, 9};
    int Ks[7] = {512, 512, 512, 512, 512, 256, 512};
    int isA[7] = {1, 0, 0, 0, 0, 0, 0};
    int pss[7] = {524288, 131072, 262144, 262144, 262144, 131072, 262144};
    int s = 0;
    for (int i = 0; i < 7; ++i) {
      pj.src[i] = srcs[i];
      pj.dst[i] = dsts[i];
      pj.N[i] = Ns[i];
      pj.logN[i] = logNs[i];
      pj.isA[i] = isA[i];
      pj.ps[i] = pss[i];
      pj.start[i] = s;
      s += isA[i] ? 1024 * (Ks[i] / 8) : (Ks[i] / 8) * Ns[i];
    }
    pj.start[7] = s;
    pack_all<<<(s + 255) / 256, 256, 0, stream>>>(pj);
  }

  auto normTile = [](const u16* pB, int N, int n0, float* C, int ldc, int bps) {
    TileDesc td{};
    td.Blo = pB + n0 * 8;
    td.Bhi = pB + (n0 + 64) * 8;
    td.ldNlo = td.ldNhi = N;
    td.Clo = C + n0;
    td.Chi = C + n0 + 64;
    td.ldClo = td.ldChi = ldc;
    td.mode = 0;
    td.bps = bps;
    return td;
  };

  // ---- K1: h @ {W_dq(mode2), W_csa_kv, W_csa_z, W_swkv} (MT=64 tiles) ----
  {
    GemmArgs ga{};
    int nt = 0;
    for (int n0 = 0; n0 < 256; n0 += 128) {
      TileDesc td = normTile(pWdq, 256, n0, q_lat, 256, 131072);
      td.mode = 2;
      td.Cp = qlP;
      td.cpps = 262144;
      td.n0 = n0;
      ga.d[nt++] = td;
    }
    for (int n0 = 0; n0 < 512; n0 += 128) ga.d[nt++] = normTile(pWckv, 512, n0, hckv, 512, 262144);
    for (int n0 = 0; n0 < 512; n0 += 128) ga.d[nt++] = normTile(pWcz, 512, n0, hcz, 512, 262144);
    for (int n0 = 0; n0 < 512; n0 += 128) ga.d[nt++] = normTile(pWsw, 512, n0, kvb, 512, 262144);
    gemm_bf16<2><<<dim3(nt, 16), 256, 0, stream>>>(hA, 16, 524288, ga);
  }
  // ---- merged K2 (q_lat @ W_uq) + idx-path GEMMs ----
  {
    GemmArgs ga{};
    int nt = 0;
    for (int n0 = 0; n0 < 512; n0 += 128) ga.d[nt++] = normTile(pWuq, 512, n0, qbuf, 512, 131072);
    k2idx_kernel<<<64 + Tn / 4, 256, 0, stream>>>(qlP, 262144, ga, h, q_lat,
                                                  W_idx_kv, W_idx_z, W_iuq,
                                                  hikv, hiz, qib);
  }
  // ---- merged phrase aggregation + q/k_sw rms+rope ----
  phrase_rope_kernel<<<Pn + Tn, 512, 0, stream>>>(
      mask, tok, endp, hckv, hcz, hikv, hiz, B_csa, B_idx, knw, qnw, ccsa,
      kcsa, kidx, qbuf, kvb, kswb);
  // ---- scores + top-32 ----
  score_topk_kernel<<<Tn, 128, 0, stream>>>(h, W_w, qib, kidx, endp, seli,
                                            selok);
  // ---- attention v5 (8 consecutive t per block, one head) ----
  attn8_kernel<<<dim3(Tn / 8 * Hn), 512, 0, stream>>>(qbuf, kswb, kvb, kcsa,
                                                      ccsa, seli, selok, sink,
                                                      atP);
  // ---- K7: attno @ W_o -> out ----
  {
    GemmArgs ga{};
    int nt = 0;
    for (int n0 = 0; n0 < 512; n0 += 128) ga.d[nt++] = normTile(pWo, 512, n0, outp, 512, 262144);
    gemm_bf16<2><<<dim3(nt, 16), 256, 0, stream>>>(atP, 16, 524288, ga);
  }
  (void)in_sizes; (void)n_in; (void)out_size; (void)ws_size;
}